// Round 1
// baseline (338.428 us; speedup 1.0000x reference)
//
#include <hip/hip_runtime.h>

// AGDN graph layer, fused. B=8, L=256, H=128, E=32.
// Key refactorings:
//  - edge_h never materialized: Wea = We2@Wa_edge, Wem = We2@Wm_edge precomputed.
//  - Wm2 hoisted out of the pair loop (softmax weights sum to 1).
//  - invalid rows (valid_mask[b,i]==0) skipped entirely (output row is zeroed anyway).

typedef __attribute__((ext_vector_type(8))) short bhalf8;  // 8 bf16 in 4 VGPRs
typedef __attribute__((ext_vector_type(4))) float f32x4;

__device__ __forceinline__ short f2bf(float f) {
  union { float f; unsigned u; } v; v.f = f;
  unsigned r = (v.u + 0x7FFFu + ((v.u >> 16) & 1u)) >> 16;  // RNE
  return (short)r;
}

__device__ __forceinline__ f32x4 mfma16(bhalf8 a, bhalf8 b, f32x4 c) {
  return __builtin_amdgcn_mfma_f32_16x16x32_bf16(a, b, c, 0, 0, 0);
}

// ---------------------------------------------------------------------------
// Kernel A: pack We1 (bf16, B-frag layout), compute Wea=We2@Wa_edge and
// Wem=We2@Wm_edge packed bf16 B-frag layout; bea=be2@Wa_edge+ba1, bem=be2@Wm_edge+bm1.
// B-frag layout for 16x16x32: element (e=0..7) of lane l is W[k][n],
// k = 32*ks + 8*(l>>4) + e, n = 16*nt + (l&15); flat idx ((ks*8+nt)*64+l)*8+e.
// ---------------------------------------------------------------------------
__global__ void kernA(const float* __restrict__ We1, const float* __restrict__ We2,
                      const float* __restrict__ be2, const float* __restrict__ Wa1,
                      const float* __restrict__ ba1, const float* __restrict__ Wm1,
                      const float* __restrict__ bm1,
                      short* __restrict__ we1p, short* __restrict__ weap,
                      short* __restrict__ wemp, float* __restrict__ bea,
                      float* __restrict__ bem) {
  int u = blockIdx.x * 256 + threadIdx.x;
  if (u < 4096) {                       // pack We1 (K=32, single k-step)
    int e = u & 7, lane = (u >> 3) & 63, nt = u >> 9;
    int k = 8 * (lane >> 4) + e, n = 16 * nt + (lane & 15);
    we1p[u] = f2bf(We1[k * 128 + n]);
  } else if (u < 20480) {               // Wea = We2 @ Wa1[256:384] packed
    int v = u - 4096;
    int e = v & 7, lane = (v >> 3) & 63, nt = (v >> 9) & 7, ks = v >> 12;
    int k = 32 * ks + 8 * (lane >> 4) + e, n = 16 * nt + (lane & 15);
    float acc = 0.f;
    for (int c = 0; c < 128; ++c)
      acc = fmaf(We2[k * 128 + c], Wa1[(256 + c) * 128 + n], acc);
    weap[v] = f2bf(acc);
  } else if (u < 36864) {               // Wem = We2 @ Wm1[128:256] packed
    int v = u - 20480;
    int e = v & 7, lane = (v >> 3) & 63, nt = (v >> 9) & 7, ks = v >> 12;
    int k = 32 * ks + 8 * (lane >> 4) + e, n = 16 * nt + (lane & 15);
    float acc = 0.f;
    for (int c = 0; c < 128; ++c)
      acc = fmaf(We2[k * 128 + c], Wm1[(128 + c) * 128 + n], acc);
    wemp[v] = f2bf(acc);
  } else if (u < 36992) {               // bea = be2 @ Wa_edge + ba1
    int hc = u - 36864;
    float acc = ba1[hc];
    for (int c = 0; c < 128; ++c) acc = fmaf(be2[c], Wa1[(256 + c) * 128 + hc], acc);
    bea[hc] = acc;
  } else if (u < 37120) {               // bem = be2 @ Wm_edge + bm1
    int hc = u - 36992;
    float acc = bm1[hc];
    for (int c = 0; c < 128; ++c) acc = fmaf(be2[c], Wm1[(128 + c) * 128 + hc], acc);
    bem[hc] = acc;
  }
}

// ---------------------------------------------------------------------------
// Kernel B: per node (8 per block): asrcb = h@Wa_src + bea, adst = h@Wa_dst,
// hmb = h@Wm_src + bem.
// ---------------------------------------------------------------------------
__global__ __launch_bounds__(128) void kernB(
    const float* __restrict__ hsrc, const float* __restrict__ Wa1,
    const float* __restrict__ Wm1, const float* __restrict__ bea,
    const float* __restrict__ bem, float* __restrict__ asrcb,
    float* __restrict__ adst, float* __restrict__ hmb) {
  __shared__ float hL[8][128];
  const int tid = threadIdx.x;
  const int base = blockIdx.x * 8;
  for (int g = 0; g < 8; ++g) hL[g][tid] = hsrc[(size_t)(base + g) * 128 + tid];
  __syncthreads();
  float aS[8], aD[8], aM[8];
#pragma unroll
  for (int g = 0; g < 8; ++g) { aS[g] = 0.f; aD[g] = 0.f; aM[g] = 0.f; }
  for (int k = 0; k < 128; k += 4) {
    float s0 = Wa1[(k + 0) * 128 + tid], s1 = Wa1[(k + 1) * 128 + tid];
    float s2 = Wa1[(k + 2) * 128 + tid], s3 = Wa1[(k + 3) * 128 + tid];
    float d0 = Wa1[(128 + k + 0) * 128 + tid], d1 = Wa1[(128 + k + 1) * 128 + tid];
    float d2 = Wa1[(128 + k + 2) * 128 + tid], d3 = Wa1[(128 + k + 3) * 128 + tid];
    float m0 = Wm1[(k + 0) * 128 + tid], m1 = Wm1[(k + 1) * 128 + tid];
    float m2 = Wm1[(k + 2) * 128 + tid], m3 = Wm1[(k + 3) * 128 + tid];
#pragma unroll
    for (int g = 0; g < 8; ++g) {
      const float4 hv = *(const float4*)&hL[g][k];
      aS[g] = fmaf(hv.x, s0, fmaf(hv.y, s1, fmaf(hv.z, s2, fmaf(hv.w, s3, aS[g]))));
      aD[g] = fmaf(hv.x, d0, fmaf(hv.y, d1, fmaf(hv.z, d2, fmaf(hv.w, d3, aD[g]))));
      aM[g] = fmaf(hv.x, m0, fmaf(hv.y, m1, fmaf(hv.z, m2, fmaf(hv.w, m3, aM[g]))));
    }
  }
  const float beav = bea[tid], bemv = bem[tid];
  for (int g = 0; g < 8; ++g) {
    size_t o = (size_t)(base + g) * 128 + tid;
    asrcb[o] = aS[g] + beav;
    adst[o] = aD[g];
    hmb[o] = aM[g] + bemv;
  }
}

// ---------------------------------------------------------------------------
// Kernel C: per valid node (b,i): fused T / attention / message with online
// softmax over two 128-j tiles. 4 waves; wave w: j-block (w>>1), h-half (w&1);
// wave tile = 64j x 64h = 4x4 fragments of 16x16.
// ---------------------------------------------------------------------------
__global__ __launch_bounds__(256, 2) void kernC(
    const float* __restrict__ ef, const int* __restrict__ vmask,
    const short* __restrict__ we1p, const short* __restrict__ weap,
    const short* __restrict__ wemp, const float* __restrict__ asrcb,
    const float* __restrict__ adst, const float* __restrict__ hmb,
    const float* __restrict__ wa2, const float* __restrict__ be1,
    const float* __restrict__ ba2, float* __restrict__ aggw) {
  const int blk = blockIdx.x;        // b*256 + i
  const int b = blk >> 8;
  if (vmask[blk] == 0) return;       // invalid row: output zeroed in kernD

  __shared__ short Tl[128 * 128];    // 32KB bf16, XOR-swizzled rows
  __shared__ float att2[2][128];     // per-h-half partial attention logits
  __shared__ float wtil[128];        // unnormalized softmax weights (tile)
  __shared__ float asr_s[128], hm_s[128], wa2_s[128], be1_s[128];
  __shared__ float agg2[2][128];     // per-jb-half partial aggregation
  __shared__ float scale_sh, invl_sh;

  const int tid = threadIdx.x;
  const int w = tid >> 6, l = tid & 63;
  const int l15 = l & 15, l4 = l >> 4;
  const int jbw = w >> 1, hh = w & 1;

  if (tid < 128) {
    asr_s[tid] = asrcb[(size_t)blk * 128 + tid];
    hm_s[tid] = hmb[(size_t)blk * 128 + tid];
    wa2_s[tid] = wa2[tid];
    be1_s[tid] = be1[tid];
    agg2[0][tid] = 0.f;
    agg2[1][tid] = 0.f;
  }
  __syncthreads();

  float m_run = -INFINITY, l_run = 0.f;   // wave0's online-softmax state
  const float ba2v = ba2[0];
  const float RS = 0.08838834764831845f;  // 1/sqrt(128)
  const f32x4 vz = {0.f, 0.f, 0.f, 0.f};

  for (int t = 0; t < 2; ++t) {
    // ---------------- phase 1: T = relu(EF @ We1 + be1) -> Tl ----------------
    const int jbg = t * 2 + jbw;
    f32x4 acc[4][4];
#pragma unroll
    for (int m = 0; m < 4; ++m)
#pragma unroll
      for (int n = 0; n < 4; ++n) acc[m][n] = vz;

    bhalf8 bfr[4];
#pragma unroll
    for (int n = 0; n < 4; ++n) {
      int nt = hh * 4 + n;
      bfr[n] = *(const bhalf8*)(we1p + (size_t)(nt * 64 + l) * 8);
    }
#pragma unroll
    for (int m = 0; m < 4; ++m) {
      int j = jbg * 64 + 16 * m + l15;
      const float* p = ef + (((size_t)blk * 256 + j) * 32 + 8 * l4);
      float4 f0 = *(const float4*)p;
      float4 f1 = *(const float4*)(p + 4);
      bhalf8 a;
      a[0] = f2bf(f0.x); a[1] = f2bf(f0.y); a[2] = f2bf(f0.z); a[3] = f2bf(f0.w);
      a[4] = f2bf(f1.x); a[5] = f2bf(f1.y); a[6] = f2bf(f1.z); a[7] = f2bf(f1.w);
#pragma unroll
      for (int n = 0; n < 4; ++n) acc[m][n] = mfma16(a, bfr[n], acc[m][n]);
    }
#pragma unroll
    for (int m = 0; m < 4; ++m)
#pragma unroll
      for (int n = 0; n < 4; ++n) {
        int hc = hh * 64 + 16 * n + l15;
        float bias = be1_s[hc];
#pragma unroll
        for (int r = 0; r < 4; ++r) {
          int jl = jbw * 64 + 16 * m + 4 * l4 + r;
          float v = fmaxf(acc[m][n][r] + bias, 0.f);
          int byte = (jl * 256 + 2 * hc) ^ ((jl & 7) << 4);
          *(short*)((char*)Tl + byte) = f2bf(v);
        }
      }
    __syncthreads();

    // ---------------- phase 2: EA = T @ Wea ; att logits ----------------
#pragma unroll
    for (int m = 0; m < 4; ++m)
#pragma unroll
      for (int n = 0; n < 4; ++n) acc[m][n] = vz;
#pragma unroll
    for (int ks = 0; ks < 4; ++ks) {
      bhalf8 af[4], bf2[4];
#pragma unroll
      for (int m = 0; m < 4; ++m) {
        int jl = jbw * 64 + 16 * m + l15;
        int byte = (jl * 256 + ks * 64 + 16 * l4) ^ ((jl & 7) << 4);
        af[m] = *(const bhalf8*)((const char*)Tl + byte);
      }
#pragma unroll
      for (int n = 0; n < 4; ++n) {
        int nt = hh * 4 + n;
        bf2[n] = *(const bhalf8*)(weap + (size_t)((ks * 8 + nt) * 64 + l) * 8);
      }
#pragma unroll
      for (int m = 0; m < 4; ++m)
#pragma unroll
        for (int n = 0; n < 4; ++n) acc[m][n] = mfma16(af[m], bf2[n], acc[m][n]);
    }
    {
      float asv[4], wav[4];
#pragma unroll
      for (int n = 0; n < 4; ++n) {
        int hc = hh * 64 + 16 * n + l15;
        asv[n] = asr_s[hc];
        wav[n] = wa2_s[hc];
      }
#pragma unroll
      for (int m = 0; m < 4; ++m) {
#pragma unroll
        for (int r = 0; r < 4; ++r) {
          int jl = jbw * 64 + 16 * m + 4 * l4 + r;
          int jg = t * 128 + jl;
          const float* ap = adst + ((size_t)(b * 256 + jg)) * 128 + hh * 64;
          float rp = 0.f;
#pragma unroll
          for (int n = 0; n < 4; ++n) {
            float x = acc[m][n][r] + asv[n] + ap[16 * n + l15];
            float e2 = __expf(2.f * x);
            float th = 1.f - __fdividef(2.f, e2 + 1.f);  // tanh(x)
            rp = fmaf(th, wav[n], rp);
          }
          rp += __shfl_xor(rp, 1);
          rp += __shfl_xor(rp, 2);
          rp += __shfl_xor(rp, 4);
          rp += __shfl_xor(rp, 8);
          if (l15 == 0) att2[hh][jl] = rp;
        }
      }
    }
    __syncthreads();

    // ---------------- softmax merge (wave 0) ----------------
    if (w == 0) {
      float s0, s1;
      {
        int jg = t * 128 + l;
        s0 = (att2[0][l] + att2[1][l] + ba2v) * RS;
        if (vmask[b * 256 + jg] == 0) s0 = -1e9f;
        jg = t * 128 + l + 64;
        s1 = (att2[0][l + 64] + att2[1][l + 64] + ba2v) * RS;
        if (vmask[b * 256 + jg] == 0) s1 = -1e9f;
      }
      float mt = fmaxf(s0, s1);
#pragma unroll
      for (int o = 1; o < 64; o <<= 1) mt = fmaxf(mt, __shfl_xor(mt, o));
      float mnew = fmaxf(m_run, mt);
      float scale = __expf(m_run - mnew);   // 0 on first tile (m_run=-inf)
      float e0 = __expf(s0 - mnew), e1 = __expf(s1 - mnew);
      wtil[l] = e0;
      wtil[l + 64] = e1;
      float sm = e0 + e1;
#pragma unroll
      for (int o = 1; o < 64; o <<= 1) sm += __shfl_xor(sm, o);
      l_run = l_run * scale + sm;
      m_run = mnew;
      if (l == 0) scale_sh = scale;
    }
    __syncthreads();
    agg2[tid >> 7][tid & 127] *= scale_sh;
    __syncthreads();

    // ---------------- phase 3: EM = T @ Wem ; weighted relu-agg ----------------
#pragma unroll
    for (int m = 0; m < 4; ++m)
#pragma unroll
      for (int n = 0; n < 4; ++n) acc[m][n] = vz;
#pragma unroll
    for (int ks = 0; ks < 4; ++ks) {
      bhalf8 af[4], bf2[4];
#pragma unroll
      for (int m = 0; m < 4; ++m) {
        int jl = jbw * 64 + 16 * m + l15;
        int byte = (jl * 256 + ks * 64 + 16 * l4) ^ ((jl & 7) << 4);
        af[m] = *(const bhalf8*)((const char*)Tl + byte);
      }
#pragma unroll
      for (int n = 0; n < 4; ++n) {
        int nt = hh * 4 + n;
        bf2[n] = *(const bhalf8*)(wemp + (size_t)((ks * 8 + nt) * 64 + l) * 8);
      }
#pragma unroll
      for (int m = 0; m < 4; ++m)
#pragma unroll
        for (int n = 0; n < 4; ++n) acc[m][n] = mfma16(af[m], bf2[n], acc[m][n]);
    }
    {
      float hv[4];
#pragma unroll
      for (int n = 0; n < 4; ++n) hv[n] = hm_s[hh * 64 + 16 * n + l15];
      float part[4] = {0.f, 0.f, 0.f, 0.f};
#pragma unroll
      for (int m = 0; m < 4; ++m) {
#pragma unroll
        for (int r = 0; r < 4; ++r) {
          int jl = jbw * 64 + 16 * m + 4 * l4 + r;
          float wj = wtil[jl];
#pragma unroll
          for (int n = 0; n < 4; ++n) {
            float v = fmaxf(acc[m][n][r] + hv[n], 0.f);
            part[n] = fmaf(wj, v, part[n]);
          }
        }
      }
#pragma unroll
      for (int n = 0; n < 4; ++n) {
        part[n] += __shfl_xor(part[n], 16);
        part[n] += __shfl_xor(part[n], 32);
      }
      if (l4 == 0) {
#pragma unroll
        for (int n = 0; n < 4; ++n) agg2[jbw][hh * 64 + 16 * n + l15] += part[n];
      }
    }
    __syncthreads();
  }

  if (tid == 0) invl_sh = 1.f / l_run;
  __syncthreads();
  if (tid < 128)
    aggw[(size_t)blk * 128 + tid] = (agg2[0][tid] + agg2[1][tid]) * invl_sh;
}

// ---------------------------------------------------------------------------
// Kernel D: per node (8 per block): agg2 = aggw@Wm2+bm2; u = relu(h@Wo_src +
// agg2@Wo_dst + bo1); out = u@Wo2+bo2; res = h+out; LayerNorm; mask.
// ---------------------------------------------------------------------------
__global__ __launch_bounds__(256) void kernD(
    const float* __restrict__ hsrc, const int* __restrict__ vmask,
    const float* __restrict__ aggw, const float* __restrict__ Wm2,
    const float* __restrict__ bm2, const float* __restrict__ Wo1,
    const float* __restrict__ bo1, const float* __restrict__ Wo2,
    const float* __restrict__ bo2, const float* __restrict__ gma,
    const float* __restrict__ bta, float* __restrict__ outp) {
  __shared__ float hL[8][128], xL[8][128], uL[8][128], rL[8][128];
  const int tid = threadIdx.x;
  const int col = tid & 127, g2 = tid >> 7;
  const int base = blockIdx.x * 8;
  for (int q = 0; q < 4; ++q) {
    int g = q * 2 + g2;
    int node = base + g;
    hL[g][col] = hsrc[(size_t)node * 128 + col];
    xL[g][col] = vmask[node] ? aggw[(size_t)node * 128 + col] : 0.f;
  }
  __syncthreads();
  float a4[4];
  // D1: uL = xL @ Wm2 + bm2
#pragma unroll
  for (int q = 0; q < 4; ++q) a4[q] = 0.f;
  for (int k = 0; k < 128; k += 4) {
    float w0 = Wm2[(k + 0) * 128 + col], w1 = Wm2[(k + 1) * 128 + col];
    float w2 = Wm2[(k + 2) * 128 + col], w3 = Wm2[(k + 3) * 128 + col];
#pragma unroll
    for (int q = 0; q < 4; ++q) {
      const float4 xv = *(const float4*)&xL[g2 * 4 + q][k];
      a4[q] = fmaf(xv.x, w0, fmaf(xv.y, w1, fmaf(xv.z, w2, fmaf(xv.w, w3, a4[q]))));
    }
  }
  {
    float bv = bm2[col];
#pragma unroll
    for (int q = 0; q < 4; ++q) uL[g2 * 4 + q][col] = a4[q] + bv;
  }
  __syncthreads();
  // D2: rL = relu(hL@Wo1[:128] + uL@Wo1[128:] + bo1)
#pragma unroll
  for (int q = 0; q < 4; ++q) a4[q] = 0.f;
  for (int k = 0; k < 128; k += 4) {
    float w0 = Wo1[(k + 0) * 128 + col], w1 = Wo1[(k + 1) * 128 + col];
    float w2 = Wo1[(k + 2) * 128 + col], w3 = Wo1[(k + 3) * 128 + col];
#pragma unroll
    for (int q = 0; q < 4; ++q) {
      const float4 xv = *(const float4*)&hL[g2 * 4 + q][k];
      a4[q] = fmaf(xv.x, w0, fmaf(xv.y, w1, fmaf(xv.z, w2, fmaf(xv.w, w3, a4[q]))));
    }
  }
  for (int k = 0; k < 128; k += 4) {
    float w0 = Wo1[(128 + k + 0) * 128 + col], w1 = Wo1[(128 + k + 1) * 128 + col];
    float w2 = Wo1[(128 + k + 2) * 128 + col], w3 = Wo1[(128 + k + 3) * 128 + col];
#pragma unroll
    for (int q = 0; q < 4; ++q) {
      const float4 xv = *(const float4*)&uL[g2 * 4 + q][k];
      a4[q] = fmaf(xv.x, w0, fmaf(xv.y, w1, fmaf(xv.z, w2, fmaf(xv.w, w3, a4[q]))));
    }
  }
  {
    float bv = bo1[col];
#pragma unroll
    for (int q = 0; q < 4; ++q) rL[g2 * 4 + q][col] = fmaxf(a4[q] + bv, 0.f);
  }
  __syncthreads();
  // D3: xL = hL + rL @ Wo2 + bo2   (residual)
#pragma unroll
  for (int q = 0; q < 4; ++q) a4[q] = 0.f;
  for (int k = 0; k < 128; k += 4) {
    float w0 = Wo2[(k + 0) * 128 + col], w1 = Wo2[(k + 1) * 128 + col];
    float w2 = Wo2[(k + 2) * 128 + col], w3 = Wo2[(k + 3) * 128 + col];
#pragma unroll
    for (int q = 0; q < 4; ++q) {
      const float4 xv = *(const float4*)&rL[g2 * 4 + q][k];
      a4[q] = fmaf(xv.x, w0, fmaf(xv.y, w1, fmaf(xv.z, w2, fmaf(xv.w, w3, a4[q]))));
    }
  }
  {
    float bv = bo2[col];
#pragma unroll
    for (int q = 0; q < 4; ++q)
      xL[g2 * 4 + q][col] = hL[g2 * 4 + q][col] + a4[q] + bv;
  }
  __syncthreads();
  // D4: LayerNorm + mask; wave wv handles nodes 2*wv, 2*wv+1
  const int wv = tid >> 6, ln = tid & 63;
  for (int s = 0; s < 2; ++s) {
    int g = wv * 2 + s;
    int node = base + g;
    float x0 = xL[g][ln], x1 = xL[g][ln + 64];
    float sm = x0 + x1;
#pragma unroll
    for (int o = 1; o < 64; o <<= 1) sm += __shfl_xor(sm, o);
    float mu = sm * (1.f / 128.f);
    float d0 = x0 - mu, d1 = x1 - mu;
    float vs = d0 * d0 + d1 * d1;
#pragma unroll
    for (int o = 1; o < 64; o <<= 1) vs += __shfl_xor(vs, o);
    float inv = rsqrtf(vs * (1.f / 128.f) + 1e-5f);
    int valid = vmask[node];
    float o0 = valid ? (d0 * inv * gma[ln] + bta[ln]) : 0.f;
    float o1 = valid ? (d1 * inv * gma[ln + 64] + bta[ln + 64]) : 0.f;
    outp[(size_t)node * 128 + ln] = o0;
    outp[(size_t)node * 128 + ln + 64] = o1;
  }
}

// ---------------------------------------------------------------------------
extern "C" void kernel_launch(void* const* d_in, const int* in_sizes, int n_in,
                              void* d_out, int out_size, void* d_ws, size_t ws_size,
                              hipStream_t stream) {
  const float* h_in = (const float*)d_in[0];
  const float* ef = (const float*)d_in[1];
  const int* vmask = (const int*)d_in[2];
  const float* We1 = (const float*)d_in[3];
  const float* be1 = (const float*)d_in[4];
  const float* We2 = (const float*)d_in[5];
  const float* be2 = (const float*)d_in[6];
  const float* Wa1 = (const float*)d_in[7];
  const float* ba1 = (const float*)d_in[8];
  const float* Wa2 = (const float*)d_in[9];
  const float* ba2 = (const float*)d_in[10];
  const float* Wm1 = (const float*)d_in[11];
  const float* bm1 = (const float*)d_in[12];
  const float* Wm2 = (const float*)d_in[13];
  const float* bm2 = (const float*)d_in[14];
  const float* Wo1 = (const float*)d_in[15];
  const float* bo1 = (const float*)d_in[16];
  const float* Wo2 = (const float*)d_in[17];
  const float* bo2 = (const float*)d_in[18];
  const float* gma = (const float*)d_in[19];
  const float* bta = (const float*)d_in[20];

  char* ws = (char*)d_ws;
  short* we1p = (short*)(ws + 0);                 // 8192 B
  short* weap = (short*)(ws + 8192);              // 32768 B
  short* wemp = (short*)(ws + 40960);             // 32768 B
  float* bea = (float*)(ws + 73728);              // 512 B
  float* bem = (float*)(ws + 74240);              // 512 B
  float* asrcb = (float*)(ws + 74752);            // 1 MiB
  float* adst = (float*)(ws + 74752 + 1048576);   // 1 MiB
  float* hmb = (float*)(ws + 74752 + 2 * 1048576);  // 1 MiB
  float* aggw = (float*)(ws + 74752 + 3 * 1048576); // 1 MiB

  kernA<<<dim3(145), dim3(256), 0, stream>>>(We1, We2, be2, Wa1, ba1, Wm1, bm1,
                                             we1p, weap, wemp, bea, bem);
  kernB<<<dim3(256), dim3(128), 0, stream>>>(h_in, Wa1, Wm1, bea, bem, asrcb,
                                             adst, hmb);
  kernC<<<dim3(2048), dim3(256), 0, stream>>>(ef, vmask, we1p, weap, wemp, asrcb,
                                              adst, hmb, Wa2, be1, ba2, aggw);
  kernD<<<dim3(256), dim3(256), 0, stream>>>(h_in, vmask, aggw, Wm2, bm2, Wo1,
                                             bo1, Wo2, bo2, gma, bta,
                                             (float*)d_out);
}

// Round 2
// 290.855 us; speedup vs baseline: 1.1636x; 1.1636x over previous
//
#include <hip/hip_runtime.h>

// AGDN graph layer, fused. B=8, L=256, H=128, E=32.
//  - edge_h never materialized: Wea = We2@Wa_edge, Wem = We2@Wm_edge precomputed.
//  - Wm2 hoisted out of the pair loop (softmax weights sum to 1).
//  - invalid rows skipped via compacted valid-index list.
//  - h_out columns of Wea/Wem PERMUTED (frag col 16n+l15 <-> orig 4*l15+n) so all
//    per-lane epilogue accesses (adst/asrc/wa2/hm/agg) are contiguous 4-vectors.
//  - non-online softmax: pass A computes all 256 logits, parallel softmax,
//    pass B recomputes T per tile and accumulates the message in registers.

typedef __attribute__((ext_vector_type(8))) short bhalf8;  // 8 bf16 in 4 VGPRs
typedef __attribute__((ext_vector_type(4))) float f32x4;

__device__ __forceinline__ short f2bf(float f) {
  union { float f; unsigned u; } v; v.f = f;
  unsigned r = (v.u + 0x7FFFu + ((v.u >> 16) & 1u)) >> 16;  // RNE
  return (short)r;
}
__device__ __forceinline__ float bf2f(unsigned short x) {
  union { unsigned u; float f; } t; t.u = ((unsigned)x) << 16; return t.f;
}
__device__ __forceinline__ f32x4 mfma16(bhalf8 a, bhalf8 b, f32x4 c) {
  return __builtin_amdgcn_mfma_f32_16x16x32_bf16(a, b, c, 0, 0, 0);
}

// ---------------------------------------------------------------------------
// Kernel A: pack We1 (B-frag layout, unpermuted cols = h_mid);
// Wea=We2@Wa_edge, Wem=We2@Wm_edge packed with PERMUTED h_out columns:
// fragment (ks,nt,lane,e) holds M[k][co], k=32ks+8*(lane>>4)+e,
// co = 64*(nt>>2) + 4*(lane&15) + (nt&3).
// bea=be2@Wa_edge+ba1, bem=be2@Wm_edge+bm1 (original order).
// ---------------------------------------------------------------------------
__global__ void kernA(const float* __restrict__ We1, const float* __restrict__ We2,
                      const float* __restrict__ be2, const float* __restrict__ Wa1,
                      const float* __restrict__ ba1, const float* __restrict__ Wm1,
                      const float* __restrict__ bm1,
                      short* __restrict__ we1p, short* __restrict__ weap,
                      short* __restrict__ wemp, float* __restrict__ bea,
                      float* __restrict__ bem) {
  int u = blockIdx.x * 256 + threadIdx.x;
  if (u < 4096) {                       // pack We1 (K=32, single k-step)
    int e = u & 7, lane = (u >> 3) & 63, nt = u >> 9;
    int k = 8 * (lane >> 4) + e, n = 16 * nt + (lane & 15);
    we1p[u] = f2bf(We1[k * 128 + n]);
  } else if (u < 20480) {               // Wea packed, permuted cols
    int v = u - 4096;
    int e = v & 7, lane = (v >> 3) & 63, nt = (v >> 9) & 7, ks = v >> 12;
    int k = 32 * ks + 8 * (lane >> 4) + e;
    int co = 64 * (nt >> 2) + 4 * (lane & 15) + (nt & 3);
    float acc = 0.f;
    for (int c = 0; c < 128; ++c)
      acc = fmaf(We2[k * 128 + c], Wa1[(256 + c) * 128 + co], acc);
    weap[v] = f2bf(acc);
  } else if (u < 36864) {               // Wem packed, permuted cols
    int v = u - 20480;
    int e = v & 7, lane = (v >> 3) & 63, nt = (v >> 9) & 7, ks = v >> 12;
    int k = 32 * ks + 8 * (lane >> 4) + e;
    int co = 64 * (nt >> 2) + 4 * (lane & 15) + (nt & 3);
    float acc = 0.f;
    for (int c = 0; c < 128; ++c)
      acc = fmaf(We2[k * 128 + c], Wm1[(128 + c) * 128 + co], acc);
    wemp[v] = f2bf(acc);
  } else if (u < 36992) {               // bea
    int hc = u - 36864;
    float acc = ba1[hc];
    for (int c = 0; c < 128; ++c) acc = fmaf(be2[c], Wa1[(256 + c) * 128 + hc], acc);
    bea[hc] = acc;
  } else if (u < 37120) {               // bem
    int hc = u - 36992;
    float acc = bm1[hc];
    for (int c = 0; c < 128; ++c) acc = fmaf(be2[c], Wm1[(128 + c) * 128 + hc], acc);
    bem[hc] = acc;
  }
}

// ---------------------------------------------------------------------------
// Kernel A2: order-preserving compaction of valid (b,i) indices.
// ---------------------------------------------------------------------------
__global__ void kernA2(const int* __restrict__ vmask, int* __restrict__ compact,
                       int* __restrict__ cnt) {
  __shared__ int wsum[4];
  const int tid = threadIdx.x;           // 256 threads
  int loc[8], c = 0;
#pragma unroll
  for (int q = 0; q < 8; ++q) {
    int v = vmask[tid * 8 + q] != 0;
    loc[q] = v;
    c += v;
  }
  const int l = tid & 63, w = tid >> 6;
  int pre = c;
#pragma unroll
  for (int o = 1; o < 64; o <<= 1) {
    int t = __shfl_up(pre, o);
    if (l >= o) pre += t;
  }
  if (l == 63) wsum[w] = pre;            // wave total
  __syncthreads();
  int base = 0;
  for (int q = 0; q < w; ++q) base += wsum[q];
  int off = base + pre - c;              // exclusive prefix
#pragma unroll
  for (int q = 0; q < 8; ++q)
    if (loc[q]) compact[off++] = tid * 8 + q;
  if (tid == 255) cnt[0] = off;
}

// ---------------------------------------------------------------------------
// Kernel B: per node: asrcb = h@Wa_src + bea, adst_bf = bf16(h@Wa_dst),
// hmb = h@Wm_src + bem.
// ---------------------------------------------------------------------------
__global__ __launch_bounds__(128) void kernB(
    const float* __restrict__ hsrc, const float* __restrict__ Wa1,
    const float* __restrict__ Wm1, const float* __restrict__ bea,
    const float* __restrict__ bem, float* __restrict__ asrcb,
    unsigned short* __restrict__ adst_bf, float* __restrict__ hmb) {
  __shared__ float hL[8][128];
  const int tid = threadIdx.x;
  const int base = blockIdx.x * 8;
  for (int g = 0; g < 8; ++g) hL[g][tid] = hsrc[(size_t)(base + g) * 128 + tid];
  __syncthreads();
  float aS[8], aD[8], aM[8];
#pragma unroll
  for (int g = 0; g < 8; ++g) { aS[g] = 0.f; aD[g] = 0.f; aM[g] = 0.f; }
  for (int k = 0; k < 128; k += 4) {
    float s0 = Wa1[(k + 0) * 128 + tid], s1 = Wa1[(k + 1) * 128 + tid];
    float s2 = Wa1[(k + 2) * 128 + tid], s3 = Wa1[(k + 3) * 128 + tid];
    float d0 = Wa1[(128 + k + 0) * 128 + tid], d1 = Wa1[(128 + k + 1) * 128 + tid];
    float d2 = Wa1[(128 + k + 2) * 128 + tid], d3 = Wa1[(128 + k + 3) * 128 + tid];
    float m0 = Wm1[(k + 0) * 128 + tid], m1 = Wm1[(k + 1) * 128 + tid];
    float m2 = Wm1[(k + 2) * 128 + tid], m3 = Wm1[(k + 3) * 128 + tid];
#pragma unroll
    for (int g = 0; g < 8; ++g) {
      const float4 hv = *(const float4*)&hL[g][k];
      aS[g] = fmaf(hv.x, s0, fmaf(hv.y, s1, fmaf(hv.z, s2, fmaf(hv.w, s3, aS[g]))));
      aD[g] = fmaf(hv.x, d0, fmaf(hv.y, d1, fmaf(hv.z, d2, fmaf(hv.w, d3, aD[g]))));
      aM[g] = fmaf(hv.x, m0, fmaf(hv.y, m1, fmaf(hv.z, m2, fmaf(hv.w, m3, aM[g]))));
    }
  }
  const float beav = bea[tid], bemv = bem[tid];
  for (int g = 0; g < 8; ++g) {
    size_t o = (size_t)(base + g) * 128 + tid;
    asrcb[o] = aS[g] + beav;
    adst_bf[o] = (unsigned short)f2bf(aD[g]);
    hmb[o] = aM[g] + bemv;
  }
}

// ---------------------------------------------------------------------------
// Kernel C: per valid node (compacted). 4 waves; wave w: jbw=w>>1 (64-j block
// within 128-j tile), hh=w&1 (h_out half).
// Pass A: logits for all 256 j; softmax; Pass B: message agg (T recomputed).
// ---------------------------------------------------------------------------
__global__ __launch_bounds__(256, 4) void kernC(
    const float* __restrict__ ef, const int* __restrict__ vmask,
    const int* __restrict__ compact, const int* __restrict__ cnt,
    const short* __restrict__ we1p, const short* __restrict__ weap,
    const short* __restrict__ wemp, const float* __restrict__ asrcb,
    const unsigned short* __restrict__ adst_bf, const float* __restrict__ hmb,
    const float* __restrict__ wa2, const float* __restrict__ be1,
    const float* __restrict__ ba2, float* __restrict__ aggw) {
  const int nv = cnt[0];
  if ((int)blockIdx.x >= nv) return;
  const int blk = compact[blockIdx.x];
  const int b = blk >> 8;

  __shared__ short Tl[128 * 128];                 // 32KB, XOR-swizzled rows
  __shared__ float att2[2][256];                  // per-h-half logit partials
  __shared__ float wtil[256];                     // unnormalized softmax weights
  __shared__ __align__(16) float asr_s[128], hm_s[128], wa2_s[128];
  __shared__ float be1_s[128];
  __shared__ __align__(16) float agg2[2][128];    // per-jbw partial agg
  __shared__ float redM[4], redS[4];

  const int tid = threadIdx.x;
  const int w = tid >> 6, l = tid & 63;
  const int l15 = l & 15, l4 = l >> 4;
  const int jbw = w >> 1, hh = w & 1;

  if (tid < 128) {
    asr_s[tid] = asrcb[(size_t)blk * 128 + tid];
    hm_s[tid] = hmb[(size_t)blk * 128 + tid];
    wa2_s[tid] = wa2[tid];
    be1_s[tid] = be1[tid];
  }
  __syncthreads();

  const float ba2v = ba2[0];
  const float RS = 0.08838834764831845f;          // 1/sqrt(128)
  const f32x4 vz = {0.f, 0.f, 0.f, 0.f};
  const f32x4 asv = *(const f32x4*)&asr_s[hh * 64 + 4 * l15];
  const f32x4 wav = *(const f32x4*)&wa2_s[hh * 64 + 4 * l15];

  // ---- T = relu(EF @ We1 + be1) for j-tile t -> Tl (swizzled) ----
  auto computeT = [&](int t) {
    f32x4 acc[4][4];
#pragma unroll
    for (int m = 0; m < 4; ++m)
#pragma unroll
      for (int n = 0; n < 4; ++n) acc[m][n] = vz;
    bhalf8 bfr[4];
#pragma unroll
    for (int n = 0; n < 4; ++n)
      bfr[n] = *(const bhalf8*)(we1p + (size_t)((hh * 4 + n) * 64 + l) * 8);
    const int jbg = t * 2 + jbw;
#pragma unroll
    for (int m = 0; m < 4; ++m) {
      int j = jbg * 64 + 16 * m + l15;
      const float* p = ef + (((size_t)blk * 256 + j) * 32 + 8 * l4);
      float4 f0 = *(const float4*)p;
      float4 f1 = *(const float4*)(p + 4);
      bhalf8 a;
      a[0] = f2bf(f0.x); a[1] = f2bf(f0.y); a[2] = f2bf(f0.z); a[3] = f2bf(f0.w);
      a[4] = f2bf(f1.x); a[5] = f2bf(f1.y); a[6] = f2bf(f1.z); a[7] = f2bf(f1.w);
#pragma unroll
      for (int n = 0; n < 4; ++n) acc[m][n] = mfma16(a, bfr[n], acc[m][n]);
    }
#pragma unroll
    for (int m = 0; m < 4; ++m)
#pragma unroll
      for (int n = 0; n < 4; ++n) {
        int hc = hh * 64 + 16 * n + l15;
        float bias = be1_s[hc];
#pragma unroll
        for (int r = 0; r < 4; ++r) {
          int jl = jbw * 64 + 16 * m + 4 * l4 + r;
          float v = fmaxf(acc[m][n][r] + bias, 0.f);
          int byte = (jl * 256 + 2 * hc) ^ ((jl & 7) << 4);
          *(short*)((char*)Tl + byte) = f2bf(v);
        }
      }
  };

  // =================== Pass A: attention logits ===================
  for (int t = 0; t < 2; ++t) {
    computeT(t);
    __syncthreads();

    f32x4 acc[4][4];
#pragma unroll
    for (int m = 0; m < 4; ++m)
#pragma unroll
      for (int n = 0; n < 4; ++n) acc[m][n] = vz;
#pragma unroll
    for (int ks = 0; ks < 4; ++ks) {
      bhalf8 af[4];
#pragma unroll
      for (int m = 0; m < 4; ++m) {
        int jl = jbw * 64 + 16 * m + l15;
        int byte = (jl * 256 + ks * 64 + 16 * l4) ^ ((jl & 7) << 4);
        af[m] = *(const bhalf8*)((const char*)Tl + byte);
      }
#pragma unroll
      for (int n = 0; n < 4; ++n) {
        bhalf8 bf2 = *(const bhalf8*)(weap + (size_t)((ks * 8 + hh * 4 + n) * 64 + l) * 8);
#pragma unroll
        for (int m = 0; m < 4; ++m) acc[m][n] = mfma16(af[m], bf2, acc[m][n]);
      }
    }
    // prefetch adst (bf16, contiguous 8B per lane thanks to column permutation)
    ushort4 adp[4][4];
#pragma unroll
    for (int m = 0; m < 4; ++m)
#pragma unroll
      for (int r = 0; r < 4; ++r) {
        int jg = t * 128 + jbw * 64 + 16 * m + 4 * l4 + r;
        adp[m][r] = *(const ushort4*)(adst_bf + (size_t)(b * 256 + jg) * 128 +
                                      hh * 64 + 4 * l15);
      }
#pragma unroll
    for (int m = 0; m < 4; ++m)
#pragma unroll
      for (int r = 0; r < 4; ++r) {
        float rp = 0.f;
        float ad0 = bf2f(adp[m][r].x), ad1 = bf2f(adp[m][r].y);
        float ad2 = bf2f(adp[m][r].z), ad3 = bf2f(adp[m][r].w);
        float adv[4] = {ad0, ad1, ad2, ad3};
#pragma unroll
        for (int n = 0; n < 4; ++n) {
          float x = acc[m][n][r] + asv[n] + adv[n];
          float e2 = __expf(2.f * x);
          float th = 1.f - __fdividef(2.f, e2 + 1.f);  // tanh(x)
          rp = fmaf(th, wav[n], rp);
        }
        rp += __shfl_xor(rp, 1);
        rp += __shfl_xor(rp, 2);
        rp += __shfl_xor(rp, 4);
        rp += __shfl_xor(rp, 8);
        if (l15 == 0) att2[hh][t * 128 + jbw * 64 + 16 * m + 4 * l4 + r] = rp;
      }
    __syncthreads();
  }

  // =================== softmax over all 256 j (parallel) ===================
  {
    float s = (att2[0][tid] + att2[1][tid] + ba2v) * RS;
    if (vmask[b * 256 + tid] == 0) s = -1e9f;
    float mx = s;
#pragma unroll
    for (int o = 1; o < 64; o <<= 1) mx = fmaxf(mx, __shfl_xor(mx, o));
    if (l == 0) redM[w] = mx;
    __syncthreads();
    float m = fmaxf(fmaxf(redM[0], redM[1]), fmaxf(redM[2], redM[3]));
    float e = __expf(s - m);
    wtil[tid] = e;
    float sm = e;
#pragma unroll
    for (int o = 1; o < 64; o <<= 1) sm += __shfl_xor(sm, o);
    if (l == 0) redS[w] = sm;
    __syncthreads();
  }

  // =================== Pass B: message aggregation ===================
  const f32x4 hv = *(const f32x4*)&hm_s[hh * 64 + 4 * l15];
  float part[4] = {0.f, 0.f, 0.f, 0.f};
  for (int t = 0; t < 2; ++t) {
    computeT(t);
    __syncthreads();

    f32x4 acc[4][4];
#pragma unroll
    for (int m = 0; m < 4; ++m)
#pragma unroll
      for (int n = 0; n < 4; ++n) acc[m][n] = vz;
#pragma unroll
    for (int ks = 0; ks < 4; ++ks) {
      bhalf8 af[4];
#pragma unroll
      for (int m = 0; m < 4; ++m) {
        int jl = jbw * 64 + 16 * m + l15;
        int byte = (jl * 256 + ks * 64 + 16 * l4) ^ ((jl & 7) << 4);
        af[m] = *(const bhalf8*)((const char*)Tl + byte);
      }
#pragma unroll
      for (int n = 0; n < 4; ++n) {
        bhalf8 bf2 = *(const bhalf8*)(wemp + (size_t)((ks * 8 + hh * 4 + n) * 64 + l) * 8);
#pragma unroll
        for (int m = 0; m < 4; ++m) acc[m][n] = mfma16(af[m], bf2, acc[m][n]);
      }
    }
#pragma unroll
    for (int m = 0; m < 4; ++m)
#pragma unroll
      for (int r = 0; r < 4; ++r) {
        int jl = jbw * 64 + 16 * m + 4 * l4 + r;
        float wj = wtil[t * 128 + jl];
#pragma unroll
        for (int n = 0; n < 4; ++n) {
          float v = fmaxf(acc[m][n][r] + hv[n], 0.f);
          part[n] = fmaf(wj, v, part[n]);
        }
      }
    __syncthreads();
  }

#pragma unroll
  for (int n = 0; n < 4; ++n) {
    part[n] += __shfl_xor(part[n], 16);
    part[n] += __shfl_xor(part[n], 32);
  }
  if (l4 == 0) {
    f32x4 pv = {part[0], part[1], part[2], part[3]};
    *(f32x4*)&agg2[jbw][hh * 64 + 4 * l15] = pv;
  }
  __syncthreads();
  if (tid < 128) {
    float invl = 1.f / (redS[0] + redS[1] + redS[2] + redS[3]);
    aggw[(size_t)blk * 128 + tid] = (agg2[0][tid] + agg2[1][tid]) * invl;
  }
}

// ---------------------------------------------------------------------------
// Kernel D: per node (8 per block): agg2 = aggw@Wm2+bm2; u = relu(h@Wo_src +
// agg2@Wo_dst + bo1); out = u@Wo2+bo2; res = h+out; LayerNorm; mask.
// ---------------------------------------------------------------------------
__global__ __launch_bounds__(256) void kernD(
    const float* __restrict__ hsrc, const int* __restrict__ vmask,
    const float* __restrict__ aggw, const float* __restrict__ Wm2,
    const float* __restrict__ bm2, const float* __restrict__ Wo1,
    const float* __restrict__ bo1, const float* __restrict__ Wo2,
    const float* __restrict__ bo2, const float* __restrict__ gma,
    const float* __restrict__ bta, float* __restrict__ outp) {
  __shared__ float hL[8][128], xL[8][128], uL[8][128], rL[8][128];
  const int tid = threadIdx.x;
  const int col = tid & 127, g2 = tid >> 7;
  const int base = blockIdx.x * 8;
  for (int q = 0; q < 4; ++q) {
    int g = q * 2 + g2;
    int node = base + g;
    hL[g][col] = hsrc[(size_t)node * 128 + col];
    xL[g][col] = vmask[node] ? aggw[(size_t)node * 128 + col] : 0.f;
  }
  __syncthreads();
  float a4[4];
#pragma unroll
  for (int q = 0; q < 4; ++q) a4[q] = 0.f;
  for (int k = 0; k < 128; k += 4) {
    float w0 = Wm2[(k + 0) * 128 + col], w1 = Wm2[(k + 1) * 128 + col];
    float w2 = Wm2[(k + 2) * 128 + col], w3 = Wm2[(k + 3) * 128 + col];
#pragma unroll
    for (int q = 0; q < 4; ++q) {
      const float4 xv = *(const float4*)&xL[g2 * 4 + q][k];
      a4[q] = fmaf(xv.x, w0, fmaf(xv.y, w1, fmaf(xv.z, w2, fmaf(xv.w, w3, a4[q]))));
    }
  }
  {
    float bv = bm2[col];
#pragma unroll
    for (int q = 0; q < 4; ++q) uL[g2 * 4 + q][col] = a4[q] + bv;
  }
  __syncthreads();
#pragma unroll
  for (int q = 0; q < 4; ++q) a4[q] = 0.f;
  for (int k = 0; k < 128; k += 4) {
    float w0 = Wo1[(k + 0) * 128 + col], w1 = Wo1[(k + 1) * 128 + col];
    float w2 = Wo1[(k + 2) * 128 + col], w3 = Wo1[(k + 3) * 128 + col];
#pragma unroll
    for (int q = 0; q < 4; ++q) {
      const float4 xv = *(const float4*)&hL[g2 * 4 + q][k];
      a4[q] = fmaf(xv.x, w0, fmaf(xv.y, w1, fmaf(xv.z, w2, fmaf(xv.w, w3, a4[q]))));
    }
  }
  for (int k = 0; k < 128; k += 4) {
    float w0 = Wo1[(128 + k + 0) * 128 + col], w1 = Wo1[(128 + k + 1) * 128 + col];
    float w2 = Wo1[(128 + k + 2) * 128 + col], w3 = Wo1[(128 + k + 3) * 128 + col];
#pragma unroll
    for (int q = 0; q < 4; ++q) {
      const float4 xv = *(const float4*)&uL[g2 * 4 + q][k];
      a4[q] = fmaf(xv.x, w0, fmaf(xv.y, w1, fmaf(xv.z, w2, fmaf(xv.w, w3, a4[q]))));
    }
  }
  {
    float bv = bo1[col];
#pragma unroll
    for (int q = 0; q < 4; ++q) rL[g2 * 4 + q][col] = fmaxf(a4[q] + bv, 0.f);
  }
  __syncthreads();
#pragma unroll
  for (int q = 0; q < 4; ++q) a4[q] = 0.f;
  for (int k = 0; k < 128; k += 4) {
    float w0 = Wo2[(k + 0) * 128 + col], w1 = Wo2[(k + 1) * 128 + col];
    float w2 = Wo2[(k + 2) * 128 + col], w3 = Wo2[(k + 3) * 128 + col];
#pragma unroll
    for (int q = 0; q < 4; ++q) {
      const float4 xv = *(const float4*)&rL[g2 * 4 + q][k];
      a4[q] = fmaf(xv.x, w0, fmaf(xv.y, w1, fmaf(xv.z, w2, fmaf(xv.w, w3, a4[q]))));
    }
  }
  {
    float bv = bo2[col];
#pragma unroll
    for (int q = 0; q < 4; ++q)
      xL[g2 * 4 + q][col] = hL[g2 * 4 + q][col] + a4[q] + bv;
  }
  __syncthreads();
  const int wv = tid >> 6, ln = tid & 63;
  for (int s = 0; s < 2; ++s) {
    int g = wv * 2 + s;
    int node = base + g;
    float x0 = xL[g][ln], x1 = xL[g][ln + 64];
    float sm = x0 + x1;
#pragma unroll
    for (int o = 1; o < 64; o <<= 1) sm += __shfl_xor(sm, o);
    float mu = sm * (1.f / 128.f);
    float d0 = x0 - mu, d1 = x1 - mu;
    float vs = d0 * d0 + d1 * d1;
#pragma unroll
    for (int o = 1; o < 64; o <<= 1) vs += __shfl_xor(vs, o);
    float inv = rsqrtf(vs * (1.f / 128.f) + 1e-5f);
    int valid = vmask[node];
    float o0 = valid ? (d0 * inv * gma[ln] + bta[ln]) : 0.f;
    float o1 = valid ? (d1 * inv * gma[ln + 64] + bta[ln + 64]) : 0.f;
    outp[(size_t)node * 128 + ln] = o0;
    outp[(size_t)node * 128 + ln + 64] = o1;
  }
}

// ---------------------------------------------------------------------------
extern "C" void kernel_launch(void* const* d_in, const int* in_sizes, int n_in,
                              void* d_out, int out_size, void* d_ws, size_t ws_size,
                              hipStream_t stream) {
  const float* h_in = (const float*)d_in[0];
  const float* ef = (const float*)d_in[1];
  const int* vmask = (const int*)d_in[2];
  const float* We1 = (const float*)d_in[3];
  const float* be1 = (const float*)d_in[4];
  const float* We2 = (const float*)d_in[5];
  const float* be2 = (const float*)d_in[6];
  const float* Wa1 = (const float*)d_in[7];
  const float* ba1 = (const float*)d_in[8];
  const float* Wa2 = (const float*)d_in[9];
  const float* ba2 = (const float*)d_in[10];
  const float* Wm1 = (const float*)d_in[11];
  const float* bm1 = (const float*)d_in[12];
  const float* Wm2 = (const float*)d_in[13];
  const float* bm2 = (const float*)d_in[14];
  const float* Wo1 = (const float*)d_in[15];
  const float* bo1 = (const float*)d_in[16];
  const float* Wo2 = (const float*)d_in[17];
  const float* bo2 = (const float*)d_in[18];
  const float* gma = (const float*)d_in[19];
  const float* bta = (const float*)d_in[20];

  char* ws = (char*)d_ws;
  short* we1p = (short*)(ws + 0);                    // 8192 B
  short* weap = (short*)(ws + 8192);                 // 32768 B
  short* wemp = (short*)(ws + 40960);                // 32768 B
  float* bea = (float*)(ws + 73728);                 // 512 B
  float* bem = (float*)(ws + 74240);                 // 512 B
  int* compact = (int*)(ws + 74752);                 // 8192 B
  int* cnt = (int*)(ws + 82944);                     // 64 B
  float* asrcb = (float*)(ws + 83008);               // 1 MiB
  float* hmb = (float*)(ws + 83008 + 1048576);       // 1 MiB
  unsigned short* adst_bf = (unsigned short*)(ws + 83008 + 2097152);  // 512 KiB
  float* aggw = (float*)(ws + 83008 + 2621440);      // 1 MiB

  kernA<<<dim3(145), dim3(256), 0, stream>>>(We1, We2, be2, Wa1, ba1, Wm1, bm1,
                                             we1p, weap, wemp, bea, bem);
  kernA2<<<dim3(1), dim3(256), 0, stream>>>(vmask, compact, cnt);
  kernB<<<dim3(256), dim3(128), 0, stream>>>(h_in, Wa1, Wm1, bea, bem, asrcb,
                                             adst_bf, hmb);
  kernC<<<dim3(2048), dim3(256), 0, stream>>>(ef, vmask, compact, cnt, we1p, weap,
                                              wemp, asrcb, adst_bf, hmb, Wa2, be1,
                                              ba2, aggw);
  kernD<<<dim3(256), dim3(256), 0, stream>>>(h_in, vmask, aggw, Wm2, bm2, Wo1,
                                             bo1, Wo2, bo2, gma, bta,
                                             (float*)d_out);
}

// Round 3
// 159.772 us; speedup vs baseline: 2.1182x; 1.8204x over previous
//
#include <hip/hip_runtime.h>

// AGDN graph layer, fused. B=8, L=256, H=128, E=32.
//  - edge_h never materialized: Wea = We2@Wa_edge, Wem = We2@Wm_edge precomputed.
//  - Wm2 hoisted out of the pair loop (softmax weights sum to 1).
//  - invalid rows skipped via compacted valid-index list.
//  - h_out columns of Wea/Wem PERMUTED (frag col 16n+l15 <-> orig 4*l15+n) so all
//    per-lane epilogue accesses (adst/asrc/wa2/hm/agg) are contiguous 4-vectors.
//  - T stored for BOTH j-tiles in LDS (64 KB): pass B reuses it (no recompute,
//    EF read once per block).
//  - NO min-waves launch_bounds: round-2's (256,4) capped VGPR=64 -> 252 MB of
//    scratch spill traffic. Let the allocator run free (~2 blocks/CU is fine).

typedef __attribute__((ext_vector_type(8))) short bhalf8;  // 8 bf16 in 4 VGPRs
typedef __attribute__((ext_vector_type(4))) float f32x4;

__device__ __forceinline__ short f2bf(float f) {
  union { float f; unsigned u; } v; v.f = f;
  unsigned r = (v.u + 0x7FFFu + ((v.u >> 16) & 1u)) >> 16;  // RNE
  return (short)r;
}
__device__ __forceinline__ float bf2f(unsigned short x) {
  union { unsigned u; float f; } t; t.u = ((unsigned)x) << 16; return t.f;
}
__device__ __forceinline__ f32x4 mfma16(bhalf8 a, bhalf8 b, f32x4 c) {
  return __builtin_amdgcn_mfma_f32_16x16x32_bf16(a, b, c, 0, 0, 0);
}

// ---------------------------------------------------------------------------
// Kernel A: pack We1 (B-frag layout, unpermuted cols = h_mid);
// Wea=We2@Wa_edge, Wem=We2@Wm_edge packed with PERMUTED h_out columns:
// fragment (ks,nt,lane,e) holds M[k][co], k=32ks+8*(lane>>4)+e,
// co = 64*(nt>>2) + 4*(lane&15) + (nt&3).
// ---------------------------------------------------------------------------
__global__ void kernA(const float* __restrict__ We1, const float* __restrict__ We2,
                      const float* __restrict__ be2, const float* __restrict__ Wa1,
                      const float* __restrict__ ba1, const float* __restrict__ Wm1,
                      const float* __restrict__ bm1,
                      short* __restrict__ we1p, short* __restrict__ weap,
                      short* __restrict__ wemp, float* __restrict__ bea,
                      float* __restrict__ bem) {
  int u = blockIdx.x * 256 + threadIdx.x;
  if (u < 4096) {                       // pack We1 (K=32, single k-step)
    int e = u & 7, lane = (u >> 3) & 63, nt = u >> 9;
    int k = 8 * (lane >> 4) + e, n = 16 * nt + (lane & 15);
    we1p[u] = f2bf(We1[k * 128 + n]);
  } else if (u < 20480) {               // Wea packed, permuted cols
    int v = u - 4096;
    int e = v & 7, lane = (v >> 3) & 63, nt = (v >> 9) & 7, ks = v >> 12;
    int k = 32 * ks + 8 * (lane >> 4) + e;
    int co = 64 * (nt >> 2) + 4 * (lane & 15) + (nt & 3);
    float acc = 0.f;
    for (int c = 0; c < 128; ++c)
      acc = fmaf(We2[k * 128 + c], Wa1[(256 + c) * 128 + co], acc);
    weap[v] = f2bf(acc);
  } else if (u < 36864) {               // Wem packed, permuted cols
    int v = u - 20480;
    int e = v & 7, lane = (v >> 3) & 63, nt = (v >> 9) & 7, ks = v >> 12;
    int k = 32 * ks + 8 * (lane >> 4) + e;
    int co = 64 * (nt >> 2) + 4 * (lane & 15) + (nt & 3);
    float acc = 0.f;
    for (int c = 0; c < 128; ++c)
      acc = fmaf(We2[k * 128 + c], Wm1[(128 + c) * 128 + co], acc);
    wemp[v] = f2bf(acc);
  } else if (u < 36992) {               // bea
    int hc = u - 36864;
    float acc = ba1[hc];
    for (int c = 0; c < 128; ++c) acc = fmaf(be2[c], Wa1[(256 + c) * 128 + hc], acc);
    bea[hc] = acc;
  } else if (u < 37120) {               // bem
    int hc = u - 36992;
    float acc = bm1[hc];
    for (int c = 0; c < 128; ++c) acc = fmaf(be2[c], Wm1[(128 + c) * 128 + hc], acc);
    bem[hc] = acc;
  }
}

// ---------------------------------------------------------------------------
// Kernel A2: order-preserving compaction of valid (b,i) indices.
// ---------------------------------------------------------------------------
__global__ void kernA2(const int* __restrict__ vmask, int* __restrict__ compact,
                       int* __restrict__ cnt) {
  __shared__ int wsum[4];
  const int tid = threadIdx.x;           // 256 threads
  int loc[8], c = 0;
#pragma unroll
  for (int q = 0; q < 8; ++q) {
    int v = vmask[tid * 8 + q] != 0;
    loc[q] = v;
    c += v;
  }
  const int l = tid & 63, w = tid >> 6;
  int pre = c;
#pragma unroll
  for (int o = 1; o < 64; o <<= 1) {
    int t = __shfl_up(pre, o);
    if (l >= o) pre += t;
  }
  if (l == 63) wsum[w] = pre;            // wave total
  __syncthreads();
  int base = 0;
  for (int q = 0; q < w; ++q) base += wsum[q];
  int off = base + pre - c;              // exclusive prefix
#pragma unroll
  for (int q = 0; q < 8; ++q)
    if (loc[q]) compact[off++] = tid * 8 + q;
  if (tid == 255) cnt[0] = off;
}

// ---------------------------------------------------------------------------
// Kernel B: per node: asrcb = h@Wa_src + bea, adst_bf = bf16(h@Wa_dst),
// hmb = h@Wm_src + bem.
// ---------------------------------------------------------------------------
__global__ __launch_bounds__(128) void kernB(
    const float* __restrict__ hsrc, const float* __restrict__ Wa1,
    const float* __restrict__ Wm1, const float* __restrict__ bea,
    const float* __restrict__ bem, float* __restrict__ asrcb,
    unsigned short* __restrict__ adst_bf, float* __restrict__ hmb) {
  __shared__ float hL[8][128];
  const int tid = threadIdx.x;
  const int base = blockIdx.x * 8;
  for (int g = 0; g < 8; ++g) hL[g][tid] = hsrc[(size_t)(base + g) * 128 + tid];
  __syncthreads();
  float aS[8], aD[8], aM[8];
#pragma unroll
  for (int g = 0; g < 8; ++g) { aS[g] = 0.f; aD[g] = 0.f; aM[g] = 0.f; }
  for (int k = 0; k < 128; k += 4) {
    float s0 = Wa1[(k + 0) * 128 + tid], s1 = Wa1[(k + 1) * 128 + tid];
    float s2 = Wa1[(k + 2) * 128 + tid], s3 = Wa1[(k + 3) * 128 + tid];
    float d0 = Wa1[(128 + k + 0) * 128 + tid], d1 = Wa1[(128 + k + 1) * 128 + tid];
    float d2 = Wa1[(128 + k + 2) * 128 + tid], d3 = Wa1[(128 + k + 3) * 128 + tid];
    float m0 = Wm1[(k + 0) * 128 + tid], m1 = Wm1[(k + 1) * 128 + tid];
    float m2 = Wm1[(k + 2) * 128 + tid], m3 = Wm1[(k + 3) * 128 + tid];
#pragma unroll
    for (int g = 0; g < 8; ++g) {
      const float4 hv = *(const float4*)&hL[g][k];
      aS[g] = fmaf(hv.x, s0, fmaf(hv.y, s1, fmaf(hv.z, s2, fmaf(hv.w, s3, aS[g]))));
      aD[g] = fmaf(hv.x, d0, fmaf(hv.y, d1, fmaf(hv.z, d2, fmaf(hv.w, d3, aD[g]))));
      aM[g] = fmaf(hv.x, m0, fmaf(hv.y, m1, fmaf(hv.z, m2, fmaf(hv.w, m3, aM[g]))));
    }
  }
  const float beav = bea[tid], bemv = bem[tid];
  for (int g = 0; g < 8; ++g) {
    size_t o = (size_t)(base + g) * 128 + tid;
    asrcb[o] = aS[g] + beav;
    adst_bf[o] = (unsigned short)f2bf(aD[g]);
    hmb[o] = aM[g] + bemv;
  }
}

// ---------------------------------------------------------------------------
// Kernel C: per valid node (compacted). 4 waves; wave w: jbw=w>>1 (64-j block
// within 128-j tile), hh=w&1 (h half).
// T for both tiles kept in LDS; pass A logits -> softmax -> pass B message.
// ---------------------------------------------------------------------------
__global__ __launch_bounds__(256) void kernC(
    const float* __restrict__ ef, const int* __restrict__ vmask,
    const int* __restrict__ compact, const int* __restrict__ cnt,
    const short* __restrict__ we1p, const short* __restrict__ weap,
    const short* __restrict__ wemp, const float* __restrict__ asrcb,
    const unsigned short* __restrict__ adst_bf, const float* __restrict__ hmb,
    const float* __restrict__ wa2, const float* __restrict__ be1,
    const float* __restrict__ ba2, float* __restrict__ aggw) {
  const int nv = cnt[0];
  if ((int)blockIdx.x >= nv) return;
  const int blk = compact[blockIdx.x];
  const int b = blk >> 8;

  __shared__ short Tl[2][128 * 128];              // 64KB, XOR-swizzled rows
  __shared__ float att2[2][256];                  // per-h-half logit partials
  __shared__ float wtil[256];                     // unnormalized softmax weights
  __shared__ __align__(16) float asr_s[128], hm_s[128], wa2_s[128];
  __shared__ float be1_s[128];
  __shared__ __align__(16) float agg2[2][128];    // per-jbw partial agg
  __shared__ float redM[4], redS[4];

  const int tid = threadIdx.x;
  const int w = tid >> 6, l = tid & 63;
  const int l15 = l & 15, l4 = l >> 4;
  const int jbw = w >> 1, hh = w & 1;

  if (tid < 128) {
    asr_s[tid] = asrcb[(size_t)blk * 128 + tid];
    hm_s[tid] = hmb[(size_t)blk * 128 + tid];
    wa2_s[tid] = wa2[tid];
    be1_s[tid] = be1[tid];
  }
  __syncthreads();

  const float ba2v = ba2[0];
  const float RS = 0.08838834764831845f;          // 1/sqrt(128)
  const f32x4 vz = {0.f, 0.f, 0.f, 0.f};
  const f32x4 asv = *(const f32x4*)&asr_s[hh * 64 + 4 * l15];
  const f32x4 wav = *(const f32x4*)&wa2_s[hh * 64 + 4 * l15];

  // ---- T = relu(EF @ We1 + be1) for j-tile t -> Tl[t] (swizzled) ----
  auto computeT = [&](int t) {
    f32x4 acc[4][4];
#pragma unroll
    for (int m = 0; m < 4; ++m)
#pragma unroll
      for (int n = 0; n < 4; ++n) acc[m][n] = vz;
    bhalf8 bfr[4];
#pragma unroll
    for (int n = 0; n < 4; ++n)
      bfr[n] = *(const bhalf8*)(we1p + (size_t)((hh * 4 + n) * 64 + l) * 8);
    const int jbg = t * 2 + jbw;
#pragma unroll
    for (int m = 0; m < 4; ++m) {
      int j = jbg * 64 + 16 * m + l15;
      const float* p = ef + (((size_t)blk * 256 + j) * 32 + 8 * l4);
      float4 f0 = *(const float4*)p;
      float4 f1 = *(const float4*)(p + 4);
      bhalf8 a;
      a[0] = f2bf(f0.x); a[1] = f2bf(f0.y); a[2] = f2bf(f0.z); a[3] = f2bf(f0.w);
      a[4] = f2bf(f1.x); a[5] = f2bf(f1.y); a[6] = f2bf(f1.z); a[7] = f2bf(f1.w);
#pragma unroll
      for (int n = 0; n < 4; ++n) acc[m][n] = mfma16(a, bfr[n], acc[m][n]);
    }
    char* Tb = (char*)Tl[t];
#pragma unroll
    for (int m = 0; m < 4; ++m)
#pragma unroll
      for (int n = 0; n < 4; ++n) {
        int hc = hh * 64 + 16 * n + l15;
        float bias = be1_s[hc];
#pragma unroll
        for (int r = 0; r < 4; ++r) {
          int jl = jbw * 64 + 16 * m + 4 * l4 + r;
          float v = fmaxf(acc[m][n][r] + bias, 0.f);
          int byte = (jl * 256 + 2 * hc) ^ ((jl & 7) << 4);
          *(short*)(Tb + byte) = f2bf(v);
        }
      }
  };

  // =================== Pass A: attention logits ===================
  for (int t = 0; t < 2; ++t) {
    computeT(t);
    __syncthreads();

    // issue adst prefetch early (contiguous 8B per lane via col permutation)
    ushort4 adp[4][4];
#pragma unroll
    for (int m = 0; m < 4; ++m)
#pragma unroll
      for (int r = 0; r < 4; ++r) {
        int jg = t * 128 + jbw * 64 + 16 * m + 4 * l4 + r;
        adp[m][r] = *(const ushort4*)(adst_bf + (size_t)(b * 256 + jg) * 128 +
                                      hh * 64 + 4 * l15);
      }

    f32x4 acc[4][4];
#pragma unroll
    for (int m = 0; m < 4; ++m)
#pragma unroll
      for (int n = 0; n < 4; ++n) acc[m][n] = vz;
    const char* Tb = (const char*)Tl[t];
#pragma unroll
    for (int ks = 0; ks < 4; ++ks) {
      bhalf8 af[4];
#pragma unroll
      for (int m = 0; m < 4; ++m) {
        int jl = jbw * 64 + 16 * m + l15;
        int byte = (jl * 256 + ks * 64 + 16 * l4) ^ ((jl & 7) << 4);
        af[m] = *(const bhalf8*)(Tb + byte);
      }
#pragma unroll
      for (int n = 0; n < 4; ++n) {
        bhalf8 bf2 = *(const bhalf8*)(weap + (size_t)((ks * 8 + hh * 4 + n) * 64 + l) * 8);
#pragma unroll
        for (int m = 0; m < 4; ++m) acc[m][n] = mfma16(af[m], bf2, acc[m][n]);
      }
    }
#pragma unroll
    for (int m = 0; m < 4; ++m)
#pragma unroll
      for (int r = 0; r < 4; ++r) {
        float rp = 0.f;
        float adv[4] = {bf2f(adp[m][r].x), bf2f(adp[m][r].y),
                        bf2f(adp[m][r].z), bf2f(adp[m][r].w)};
#pragma unroll
        for (int n = 0; n < 4; ++n) {
          float x = acc[m][n][r] + asv[n] + adv[n];
          float e2 = __expf(2.f * x);
          float th = 1.f - __fdividef(2.f, e2 + 1.f);  // tanh(x)
          rp = fmaf(th, wav[n], rp);
        }
        rp += __shfl_xor(rp, 1);
        rp += __shfl_xor(rp, 2);
        rp += __shfl_xor(rp, 4);
        rp += __shfl_xor(rp, 8);
        if (l15 == 0) att2[hh][t * 128 + jbw * 64 + 16 * m + 4 * l4 + r] = rp;
      }
  }
  __syncthreads();

  // =================== softmax over all 256 j (parallel) ===================
  {
    float s = (att2[0][tid] + att2[1][tid] + ba2v) * RS;
    if (vmask[b * 256 + tid] == 0) s = -1e9f;
    float mx = s;
#pragma unroll
    for (int o = 1; o < 64; o <<= 1) mx = fmaxf(mx, __shfl_xor(mx, o));
    if (l == 0) redM[w] = mx;
    __syncthreads();
    float m = fmaxf(fmaxf(redM[0], redM[1]), fmaxf(redM[2], redM[3]));
    float e = __expf(s - m);
    wtil[tid] = e;
    float sm = e;
#pragma unroll
    for (int o = 1; o < 64; o <<= 1) sm += __shfl_xor(sm, o);
    if (l == 0) redS[w] = sm;
    __syncthreads();
  }

  // =================== Pass B: message aggregation ===================
  const f32x4 hv = *(const f32x4*)&hm_s[hh * 64 + 4 * l15];
  float part[4] = {0.f, 0.f, 0.f, 0.f};
#pragma unroll
  for (int t = 0; t < 2; ++t) {
    f32x4 acc[4][4];
#pragma unroll
    for (int m = 0; m < 4; ++m)
#pragma unroll
      for (int n = 0; n < 4; ++n) acc[m][n] = vz;
    const char* Tb = (const char*)Tl[t];
#pragma unroll
    for (int ks = 0; ks < 4; ++ks) {
      bhalf8 af[4];
#pragma unroll
      for (int m = 0; m < 4; ++m) {
        int jl = jbw * 64 + 16 * m + l15;
        int byte = (jl * 256 + ks * 64 + 16 * l4) ^ ((jl & 7) << 4);
        af[m] = *(const bhalf8*)(Tb + byte);
      }
#pragma unroll
      for (int n = 0; n < 4; ++n) {
        bhalf8 bf2 = *(const bhalf8*)(wemp + (size_t)((ks * 8 + hh * 4 + n) * 64 + l) * 8);
#pragma unroll
        for (int m = 0; m < 4; ++m) acc[m][n] = mfma16(af[m], bf2, acc[m][n]);
      }
    }
#pragma unroll
    for (int m = 0; m < 4; ++m)
#pragma unroll
      for (int r = 0; r < 4; ++r) {
        int jl = jbw * 64 + 16 * m + 4 * l4 + r;
        float wj = wtil[t * 128 + jl];
#pragma unroll
        for (int n = 0; n < 4; ++n) {
          float v = fmaxf(acc[m][n][r] + hv[n], 0.f);
          part[n] = fmaf(wj, v, part[n]);
        }
      }
  }

#pragma unroll
  for (int n = 0; n < 4; ++n) {
    part[n] += __shfl_xor(part[n], 16);
    part[n] += __shfl_xor(part[n], 32);
  }
  if (l4 == 0) {
    f32x4 pv = {part[0], part[1], part[2], part[3]};
    *(f32x4*)&agg2[jbw][hh * 64 + 4 * l15] = pv;
  }
  __syncthreads();
  if (tid < 128) {
    float invl = 1.f / (redS[0] + redS[1] + redS[2] + redS[3]);
    aggw[(size_t)blk * 128 + tid] = (agg2[0][tid] + agg2[1][tid]) * invl;
  }
}

// ---------------------------------------------------------------------------
// Kernel D: per node (8 per block): agg2 = aggw@Wm2+bm2; u = relu(h@Wo_src +
// agg2@Wo_dst + bo1); out = u@Wo2+bo2; res = h+out; LayerNorm; mask.
// ---------------------------------------------------------------------------
__global__ __launch_bounds__(256) void kernD(
    const float* __restrict__ hsrc, const int* __restrict__ vmask,
    const float* __restrict__ aggw, const float* __restrict__ Wm2,
    const float* __restrict__ bm2, const float* __restrict__ Wo1,
    const float* __restrict__ bo1, const float* __restrict__ Wo2,
    const float* __restrict__ bo2, const float* __restrict__ gma,
    const float* __restrict__ bta, float* __restrict__ outp) {
  __shared__ float hL[8][128], xL[8][128], uL[8][128], rL[8][128];
  const int tid = threadIdx.x;
  const int col = tid & 127, g2 = tid >> 7;
  const int base = blockIdx.x * 8;
  for (int q = 0; q < 4; ++q) {
    int g = q * 2 + g2;
    int node = base + g;
    hL[g][col] = hsrc[(size_t)node * 128 + col];
    xL[g][col] = vmask[node] ? aggw[(size_t)node * 128 + col] : 0.f;
  }
  __syncthreads();
  float a4[4];
#pragma unroll
  for (int q = 0; q < 4; ++q) a4[q] = 0.f;
  for (int k = 0; k < 128; k += 4) {
    float w0 = Wm2[(k + 0) * 128 + col], w1 = Wm2[(k + 1) * 128 + col];
    float w2 = Wm2[(k + 2) * 128 + col], w3 = Wm2[(k + 3) * 128 + col];
#pragma unroll
    for (int q = 0; q < 4; ++q) {
      const float4 xv = *(const float4*)&xL[g2 * 4 + q][k];
      a4[q] = fmaf(xv.x, w0, fmaf(xv.y, w1, fmaf(xv.z, w2, fmaf(xv.w, w3, a4[q]))));
    }
  }
  {
    float bv = bm2[col];
#pragma unroll
    for (int q = 0; q < 4; ++q) uL[g2 * 4 + q][col] = a4[q] + bv;
  }
  __syncthreads();
#pragma unroll
  for (int q = 0; q < 4; ++q) a4[q] = 0.f;
  for (int k = 0; k < 128; k += 4) {
    float w0 = Wo1[(k + 0) * 128 + col], w1 = Wo1[(k + 1) * 128 + col];
    float w2 = Wo1[(k + 2) * 128 + col], w3 = Wo1[(k + 3) * 128 + col];
#pragma unroll
    for (int q = 0; q < 4; ++q) {
      const float4 xv = *(const float4*)&hL[g2 * 4 + q][k];
      a4[q] = fmaf(xv.x, w0, fmaf(xv.y, w1, fmaf(xv.z, w2, fmaf(xv.w, w3, a4[q]))));
    }
  }
  for (int k = 0; k < 128; k += 4) {
    float w0 = Wo1[(128 + k + 0) * 128 + col], w1 = Wo1[(128 + k + 1) * 128 + col];
    float w2 = Wo1[(128 + k + 2) * 128 + col], w3 = Wo1[(128 + k + 3) * 128 + col];
#pragma unroll
    for (int q = 0; q < 4; ++q) {
      const float4 xv = *(const float4*)&uL[g2 * 4 + q][k];
      a4[q] = fmaf(xv.x, w0, fmaf(xv.y, w1, fmaf(xv.z, w2, fmaf(xv.w, w3, a4[q]))));
    }
  }
  {
    float bv = bo1[col];
#pragma unroll
    for (int q = 0; q < 4; ++q) rL[g2 * 4 + q][col] = fmaxf(a4[q] + bv, 0.f);
  }
  __syncthreads();
#pragma unroll
  for (int q = 0; q < 4; ++q) a4[q] = 0.f;
  for (int k = 0; k < 128; k += 4) {
    float w0 = Wo2[(k + 0) * 128 + col], w1 = Wo2[(k + 1) * 128 + col];
    float w2 = Wo2[(k + 2) * 128 + col], w3 = Wo2[(k + 3) * 128 + col];
#pragma unroll
    for (int q = 0; q < 4; ++q) {
      const float4 xv = *(const float4*)&rL[g2 * 4 + q][k];
      a4[q] = fmaf(xv.x, w0, fmaf(xv.y, w1, fmaf(xv.z, w2, fmaf(xv.w, w3, a4[q]))));
    }
  }
  {
    float bv = bo2[col];
#pragma unroll
    for (int q = 0; q < 4; ++q)
      xL[g2 * 4 + q][col] = hL[g2 * 4 + q][col] + a4[q] + bv;
  }
  __syncthreads();
  const int wv = tid >> 6, ln = tid & 63;
  for (int s = 0; s < 2; ++s) {
    int g = wv * 2 + s;
    int node = base + g;
    float x0 = xL[g][ln], x1 = xL[g][ln + 64];
    float sm = x0 + x1;
#pragma unroll
    for (int o = 1; o < 64; o <<= 1) sm += __shfl_xor(sm, o);
    float mu = sm * (1.f / 128.f);
    float d0 = x0 - mu, d1 = x1 - mu;
    float vs = d0 * d0 + d1 * d1;
#pragma unroll
    for (int o = 1; o < 64; o <<= 1) vs += __shfl_xor(vs, o);
    float inv = rsqrtf(vs * (1.f / 128.f) + 1e-5f);
    int valid = vmask[node];
    float o0 = valid ? (d0 * inv * gma[ln] + bta[ln]) : 0.f;
    float o1 = valid ? (d1 * inv * gma[ln + 64] + bta[ln + 64]) : 0.f;
    outp[(size_t)node * 128 + ln] = o0;
    outp[(size_t)node * 128 + ln + 64] = o1;
  }
}

// ---------------------------------------------------------------------------
extern "C" void kernel_launch(void* const* d_in, const int* in_sizes, int n_in,
                              void* d_out, int out_size, void* d_ws, size_t ws_size,
                              hipStream_t stream) {
  const float* h_in = (const float*)d_in[0];
  const float* ef = (const float*)d_in[1];
  const int* vmask = (const int*)d_in[2];
  const float* We1 = (const float*)d_in[3];
  const float* be1 = (const float*)d_in[4];
  const float* We2 = (const float*)d_in[5];
  const float* be2 = (const float*)d_in[6];
  const float* Wa1 = (const float*)d_in[7];
  const float* ba1 = (const float*)d_in[8];
  const float* Wa2 = (const float*)d_in[9];
  const float* ba2 = (const float*)d_in[10];
  const float* Wm1 = (const float*)d_in[11];
  const float* bm1 = (const float*)d_in[12];
  const float* Wm2 = (const float*)d_in[13];
  const float* bm2 = (const float*)d_in[14];
  const float* Wo1 = (const float*)d_in[15];
  const float* bo1 = (const float*)d_in[16];
  const float* Wo2 = (const float*)d_in[17];
  const float* bo2 = (const float*)d_in[18];
  const float* gma = (const float*)d_in[19];
  const float* bta = (const float*)d_in[20];

  char* ws = (char*)d_ws;
  short* we1p = (short*)(ws + 0);                    // 8192 B
  short* weap = (short*)(ws + 8192);                 // 32768 B
  short* wemp = (short*)(ws + 40960);                // 32768 B
  float* bea = (float*)(ws + 73728);                 // 512 B
  float* bem = (float*)(ws + 74240);                 // 512 B
  int* compact = (int*)(ws + 74752);                 // 8192 B
  int* cnt = (int*)(ws + 82944);                     // 64 B
  float* asrcb = (float*)(ws + 83008);               // 1 MiB
  float* hmb = (float*)(ws + 83008 + 1048576);       // 1 MiB
  unsigned short* adst_bf = (unsigned short*)(ws + 83008 + 2097152);  // 512 KiB
  float* aggw = (float*)(ws + 83008 + 2621440);      // 1 MiB

  kernA<<<dim3(145), dim3(256), 0, stream>>>(We1, We2, be2, Wa1, ba1, Wm1, bm1,
                                             we1p, weap, wemp, bea, bem);
  kernA2<<<dim3(1), dim3(256), 0, stream>>>(vmask, compact, cnt);
  kernB<<<dim3(256), dim3(128), 0, stream>>>(h_in, Wa1, Wm1, bea, bem, asrcb,
                                             adst_bf, hmb);
  kernC<<<dim3(2048), dim3(256), 0, stream>>>(ef, vmask, compact, cnt, we1p, weap,
                                              wemp, asrcb, adst_bf, hmb, Wa2, be1,
                                              ba2, aggw);
  kernD<<<dim3(256), dim3(256), 0, stream>>>(h_in, vmask, aggw, Wm2, bm2, Wo1,
                                             bo1, Wo2, bo2, gma, bta,
                                             (float*)d_out);
}

// Round 4
// 120.307 us; speedup vs baseline: 2.8130x; 1.3280x over previous
//
#include <hip/hip_runtime.h>

// AGDN graph layer, fused. B=8, L=256, H=128, E=32.
//  - edge_h never materialized: Wea = We2@Wa_edge, Wem = We2@Wm_edge precomputed.
//  - Wm2 hoisted out of the pair loop (softmax weights sum to 1).
//  - invalid rows skipped via compacted valid-index list (+rank map).
//  - h_out columns of Wea/Wem PERMUTED (frag col 16n+l15 <-> orig 4*l15+n) so all
//    per-lane epilogue accesses (adst/asrc/wa2/hm/agg) are contiguous 4-vectors.
//  - Node SPLIT across 4 blocks of 64 j each (4096 blocks): acc[2][4] halves
//    VGPR (target <=128 -> 4 waves/SIMD), LDS 20KB -> 4+ blocks/CU.
//    Partial softmax (m,s,unnormalized agg) merged in kernD (log-sum-exp).
//  - f32->bf16 via v_cvt_pk_bf16_f32 inline asm (1 op/pair vs ~4/value).

typedef __attribute__((ext_vector_type(8))) short bhalf8;  // 8 bf16 in 4 VGPRs
typedef __attribute__((ext_vector_type(4))) float f32x4;

__device__ __forceinline__ short f2bf(float f) {
  union { float f; unsigned u; } v; v.f = f;
  unsigned r = (v.u + 0x7FFFu + ((v.u >> 16) & 1u)) >> 16;  // RNE (host-side packers)
  return (short)r;
}
__device__ __forceinline__ unsigned cvt_pk(float lo, float hi) {
  unsigned r;
  asm("v_cvt_pk_bf16_f32 %0, %1, %2" : "=v"(r) : "v"(lo), "v"(hi));
  return r;
}
__device__ __forceinline__ float bf2f(unsigned short x) {
  union { unsigned u; float f; } t; t.u = ((unsigned)x) << 16; return t.f;
}
__device__ __forceinline__ f32x4 mfma16(bhalf8 a, bhalf8 b, f32x4 c) {
  return __builtin_amdgcn_mfma_f32_16x16x32_bf16(a, b, c, 0, 0, 0);
}

// ---------------------------------------------------------------------------
// Kernel A: pack We1 (B-frag layout, unpermuted cols = h_mid);
// Wea=We2@Wa_edge, Wem=We2@Wm_edge packed with PERMUTED h_out columns:
// fragment (ks,nt,lane,e) holds M[k][co], k=32ks+8*(lane>>4)+e,
// co = 64*(nt>>2) + 4*(lane&15) + (nt&3).
// ---------------------------------------------------------------------------
__global__ void kernA(const float* __restrict__ We1, const float* __restrict__ We2,
                      const float* __restrict__ be2, const float* __restrict__ Wa1,
                      const float* __restrict__ ba1, const float* __restrict__ Wm1,
                      const float* __restrict__ bm1,
                      short* __restrict__ we1p, short* __restrict__ weap,
                      short* __restrict__ wemp, float* __restrict__ bea,
                      float* __restrict__ bem) {
  int u = blockIdx.x * 256 + threadIdx.x;
  if (u < 4096) {                       // pack We1 (K=32, single k-step)
    int e = u & 7, lane = (u >> 3) & 63, nt = u >> 9;
    int k = 8 * (lane >> 4) + e, n = 16 * nt + (lane & 15);
    we1p[u] = f2bf(We1[k * 128 + n]);
  } else if (u < 20480) {               // Wea packed, permuted cols
    int v = u - 4096;
    int e = v & 7, lane = (v >> 3) & 63, nt = (v >> 9) & 7, ks = v >> 12;
    int k = 32 * ks + 8 * (lane >> 4) + e;
    int co = 64 * (nt >> 2) + 4 * (lane & 15) + (nt & 3);
    float acc = 0.f;
    for (int c = 0; c < 128; ++c)
      acc = fmaf(We2[k * 128 + c], Wa1[(256 + c) * 128 + co], acc);
    weap[v] = f2bf(acc);
  } else if (u < 36864) {               // Wem packed, permuted cols
    int v = u - 20480;
    int e = v & 7, lane = (v >> 3) & 63, nt = (v >> 9) & 7, ks = v >> 12;
    int k = 32 * ks + 8 * (lane >> 4) + e;
    int co = 64 * (nt >> 2) + 4 * (lane & 15) + (nt & 3);
    float acc = 0.f;
    for (int c = 0; c < 128; ++c)
      acc = fmaf(We2[k * 128 + c], Wm1[(128 + c) * 128 + co], acc);
    wemp[v] = f2bf(acc);
  } else if (u < 36992) {               // bea
    int hc = u - 36864;
    float acc = ba1[hc];
    for (int c = 0; c < 128; ++c) acc = fmaf(be2[c], Wa1[(256 + c) * 128 + hc], acc);
    bea[hc] = acc;
  } else if (u < 37120) {               // bem
    int hc = u - 36992;
    float acc = bm1[hc];
    for (int c = 0; c < 128; ++c) acc = fmaf(be2[c], Wm1[(128 + c) * 128 + hc], acc);
    bem[hc] = acc;
  }
}

// ---------------------------------------------------------------------------
// Kernel A2: order-preserving compaction of valid (b,i) indices + rank map.
// ---------------------------------------------------------------------------
__global__ void kernA2(const int* __restrict__ vmask, int* __restrict__ compact,
                       int* __restrict__ rmap, int* __restrict__ cnt) {
  __shared__ int wsum[4];
  const int tid = threadIdx.x;           // 256 threads
  int loc[8], c = 0;
#pragma unroll
  for (int q = 0; q < 8; ++q) {
    int v = vmask[tid * 8 + q] != 0;
    loc[q] = v;
    c += v;
  }
  const int l = tid & 63, w = tid >> 6;
  int pre = c;
#pragma unroll
  for (int o = 1; o < 64; o <<= 1) {
    int t = __shfl_up(pre, o);
    if (l >= o) pre += t;
  }
  if (l == 63) wsum[w] = pre;            // wave total
  __syncthreads();
  int base = 0;
  for (int q = 0; q < w; ++q) base += wsum[q];
  int off = base + pre - c;              // exclusive prefix
#pragma unroll
  for (int q = 0; q < 8; ++q)
    if (loc[q]) {
      rmap[tid * 8 + q] = off;
      compact[off++] = tid * 8 + q;
    }
  if (tid == 255) cnt[0] = off;
}

// ---------------------------------------------------------------------------
// Kernel B: per node: asrcb = h@Wa_src + bea, adst_bf = bf16(h@Wa_dst),
// hmb = h@Wm_src + bem.
// ---------------------------------------------------------------------------
__global__ __launch_bounds__(128) void kernB(
    const float* __restrict__ hsrc, const float* __restrict__ Wa1,
    const float* __restrict__ Wm1, const float* __restrict__ bea,
    const float* __restrict__ bem, float* __restrict__ asrcb,
    unsigned short* __restrict__ adst_bf, float* __restrict__ hmb) {
  __shared__ float hL[8][128];
  const int tid = threadIdx.x;
  const int base = blockIdx.x * 8;
  for (int g = 0; g < 8; ++g) hL[g][tid] = hsrc[(size_t)(base + g) * 128 + tid];
  __syncthreads();
  float aS[8], aD[8], aM[8];
#pragma unroll
  for (int g = 0; g < 8; ++g) { aS[g] = 0.f; aD[g] = 0.f; aM[g] = 0.f; }
  for (int k = 0; k < 128; k += 4) {
    float s0 = Wa1[(k + 0) * 128 + tid], s1 = Wa1[(k + 1) * 128 + tid];
    float s2 = Wa1[(k + 2) * 128 + tid], s3 = Wa1[(k + 3) * 128 + tid];
    float d0 = Wa1[(128 + k + 0) * 128 + tid], d1 = Wa1[(128 + k + 1) * 128 + tid];
    float d2 = Wa1[(128 + k + 2) * 128 + tid], d3 = Wa1[(128 + k + 3) * 128 + tid];
    float m0 = Wm1[(k + 0) * 128 + tid], m1 = Wm1[(k + 1) * 128 + tid];
    float m2 = Wm1[(k + 2) * 128 + tid], m3 = Wm1[(k + 3) * 128 + tid];
#pragma unroll
    for (int g = 0; g < 8; ++g) {
      const float4 hv = *(const float4*)&hL[g][k];
      aS[g] = fmaf(hv.x, s0, fmaf(hv.y, s1, fmaf(hv.z, s2, fmaf(hv.w, s3, aS[g]))));
      aD[g] = fmaf(hv.x, d0, fmaf(hv.y, d1, fmaf(hv.z, d2, fmaf(hv.w, d3, aD[g]))));
      aM[g] = fmaf(hv.x, m0, fmaf(hv.y, m1, fmaf(hv.z, m2, fmaf(hv.w, m3, aM[g]))));
    }
  }
  const float beav = bea[tid], bemv = bem[tid];
  for (int g = 0; g < 8; ++g) {
    size_t o = (size_t)(base + g) * 128 + tid;
    asrcb[o] = aS[g] + beav;
    adst_bf[o] = (unsigned short)f2bf(aD[g]);
    hmb[o] = aM[g] + bemv;
  }
}

// ---------------------------------------------------------------------------
// Kernel C: one block per (valid node, quarter q). Block handles 64 j's.
// 4 waves: wave w -> jh=w>>1 (32-j half), hh=w&1 (64-h half); tile 32j x 64h
// = 2x4 fragments. Outputs UNNORMALIZED agg + (m_loc, s_loc) for kernD merge.
// ---------------------------------------------------------------------------
__global__ __launch_bounds__(256) void kernC(
    const float* __restrict__ ef, const int* __restrict__ vmask,
    const int* __restrict__ compact, const int* __restrict__ cnt,
    const short* __restrict__ we1p, const short* __restrict__ weap,
    const short* __restrict__ wemp, const float* __restrict__ asrcb,
    const unsigned short* __restrict__ adst_bf, const float* __restrict__ hmb,
    const float* __restrict__ wa2, const float* __restrict__ be1,
    const float* __restrict__ ba2, float* __restrict__ aggp,
    float2* __restrict__ msbuf) {
  const int nv = cnt[0];
  const int v = blockIdx.x >> 2;
  if (v >= nv) return;
  const int q = blockIdx.x & 3;
  const int blk = compact[v];
  const int b = blk >> 8;

  __shared__ short Tl[64 * 128];                  // 16KB, XOR-swizzled rows
  __shared__ float att2[2][64];
  __shared__ float wtil[64];
  __shared__ __align__(16) float asr_s[128], hm_s[128], wa2_s[128];
  __shared__ float be1_s[128];
  __shared__ __align__(16) float agg2[2][128];    // per-jh partial agg

  const int tid = threadIdx.x;
  const int w = tid >> 6, l = tid & 63;
  const int l15 = l & 15, l4 = l >> 4;
  const int jh = w >> 1, hh = w & 1;

  // EF loads first (independent of LDS) to hide latency under staging.
  float4 f0[2], f1[2];
#pragma unroll
  for (int m = 0; m < 2; ++m) {
    int jl = 32 * jh + 16 * m + l15;
    const float* p = ef + (((size_t)blk * 256 + q * 64 + jl) * 32 + 8 * l4);
    f0[m] = *(const float4*)p;
    f1[m] = *(const float4*)(p + 4);
  }

  if (tid < 128) {
    asr_s[tid] = asrcb[(size_t)blk * 128 + tid];
    hm_s[tid] = hmb[(size_t)blk * 128 + tid];
    wa2_s[tid] = wa2[tid];
    be1_s[tid] = be1[tid];
  }
  __syncthreads();

  const float ba2v = ba2[0];
  const float RS = 0.08838834764831845f;          // 1/sqrt(128)
  const f32x4 vz = {0.f, 0.f, 0.f, 0.f};
  const f32x4 asv = *(const f32x4*)&asr_s[hh * 64 + 4 * l15];
  const f32x4 wav = *(const f32x4*)&wa2_s[hh * 64 + 4 * l15];

  // ---- T = relu(EF @ We1 + be1) -> Tl (swizzled) ----
  {
    f32x4 acc[2][4];
#pragma unroll
    for (int m = 0; m < 2; ++m)
#pragma unroll
      for (int n = 0; n < 4; ++n) acc[m][n] = vz;
#pragma unroll
    for (int m = 0; m < 2; ++m) {
      union { bhalf8 v8; unsigned u[4]; } a;
      a.u[0] = cvt_pk(f0[m].x, f0[m].y);
      a.u[1] = cvt_pk(f0[m].z, f0[m].w);
      a.u[2] = cvt_pk(f1[m].x, f1[m].y);
      a.u[3] = cvt_pk(f1[m].z, f1[m].w);
#pragma unroll
      for (int n = 0; n < 4; ++n) {
        bhalf8 bfr = *(const bhalf8*)(we1p + (size_t)((hh * 4 + n) * 64 + l) * 8);
        acc[m][n] = mfma16(a.v8, bfr, acc[m][n]);
      }
    }
#pragma unroll
    for (int m = 0; m < 2; ++m)
#pragma unroll
      for (int n = 0; n < 4; ++n) {
        int hc = hh * 64 + 16 * n + l15;
        float bias = be1_s[hc];
#pragma unroll
        for (int r = 0; r < 4; ++r) {
          int jl = 32 * jh + 16 * m + 4 * l4 + r;
          float vv = fmaxf(acc[m][n][r] + bias, 0.f);
          int byte = (jl * 256 + 2 * hc) ^ ((jl & 7) << 4);
          *(short*)((char*)Tl + byte) = (short)(cvt_pk(vv, vv) & 0xffff);
        }
      }
  }
  __syncthreads();

  // ---- attention logits: EA = T @ Wea ----
  {
    // adst prefetch (contiguous 8B per lane via col permutation)
    ushort4 adp[2][4];
#pragma unroll
    for (int m = 0; m < 2; ++m)
#pragma unroll
      for (int r = 0; r < 4; ++r) {
        int jg = q * 64 + 32 * jh + 16 * m + 4 * l4 + r;
        adp[m][r] = *(const ushort4*)(adst_bf + (size_t)(b * 256 + jg) * 128 +
                                      hh * 64 + 4 * l15);
      }
    f32x4 acc[2][4];
#pragma unroll
    for (int m = 0; m < 2; ++m)
#pragma unroll
      for (int n = 0; n < 4; ++n) acc[m][n] = vz;
#pragma unroll
    for (int ks = 0; ks < 4; ++ks) {
      bhalf8 af[2];
#pragma unroll
      for (int m = 0; m < 2; ++m) {
        int jl = 32 * jh + 16 * m + l15;
        int byte = (jl * 256 + ks * 64 + 16 * l4) ^ ((jl & 7) << 4);
        af[m] = *(const bhalf8*)((const char*)Tl + byte);
      }
#pragma unroll
      for (int n = 0; n < 4; ++n) {
        bhalf8 bf2 = *(const bhalf8*)(weap + (size_t)((ks * 8 + hh * 4 + n) * 64 + l) * 8);
#pragma unroll
        for (int m = 0; m < 2; ++m) acc[m][n] = mfma16(af[m], bf2, acc[m][n]);
      }
    }
#pragma unroll
    for (int m = 0; m < 2; ++m)
#pragma unroll
      for (int r = 0; r < 4; ++r) {
        float rp = 0.f;
        float adv[4] = {bf2f(adp[m][r].x), bf2f(adp[m][r].y),
                        bf2f(adp[m][r].z), bf2f(adp[m][r].w)};
#pragma unroll
        for (int n = 0; n < 4; ++n) {
          float x = acc[m][n][r] + asv[n] + adv[n];
          float e2 = __expf(2.f * x);
          float th = 1.f - __fdividef(2.f, e2 + 1.f);  // tanh(x)
          rp = fmaf(th, wav[n], rp);
        }
        rp += __shfl_xor(rp, 1);
        rp += __shfl_xor(rp, 2);
        rp += __shfl_xor(rp, 4);
        rp += __shfl_xor(rp, 8);
        if (l15 == 0) att2[hh][32 * jh + 16 * m + 4 * l4 + r] = rp;
      }
  }
  __syncthreads();

  // ---- partial softmax over this block's 64 j (wave 0) ----
  if (w == 0) {
    float s = (att2[0][l] + att2[1][l] + ba2v) * RS;
    if (vmask[b * 256 + q * 64 + l] == 0) s = -1e9f;
    float mx = s;
#pragma unroll
    for (int o = 1; o < 64; o <<= 1) mx = fmaxf(mx, __shfl_xor(mx, o));
    float e = __expf(s - mx);
    wtil[l] = e;
    float sm = e;
#pragma unroll
    for (int o = 1; o < 64; o <<= 1) sm += __shfl_xor(sm, o);
    if (l == 0) msbuf[blk * 4 + q] = make_float2(mx, sm);
  }
  __syncthreads();

  // ---- message: EM = T @ Wem ; weighted relu-agg (unnormalized) ----
  {
    const f32x4 hv = *(const f32x4*)&hm_s[hh * 64 + 4 * l15];
    f32x4 acc[2][4];
#pragma unroll
    for (int m = 0; m < 2; ++m)
#pragma unroll
      for (int n = 0; n < 4; ++n) acc[m][n] = vz;
#pragma unroll
    for (int ks = 0; ks < 4; ++ks) {
      bhalf8 af[2];
#pragma unroll
      for (int m = 0; m < 2; ++m) {
        int jl = 32 * jh + 16 * m + l15;
        int byte = (jl * 256 + ks * 64 + 16 * l4) ^ ((jl & 7) << 4);
        af[m] = *(const bhalf8*)((const char*)Tl + byte);
      }
#pragma unroll
      for (int n = 0; n < 4; ++n) {
        bhalf8 bf2 = *(const bhalf8*)(wemp + (size_t)((ks * 8 + hh * 4 + n) * 64 + l) * 8);
#pragma unroll
        for (int m = 0; m < 2; ++m) acc[m][n] = mfma16(af[m], bf2, acc[m][n]);
      }
    }
    float part[4] = {0.f, 0.f, 0.f, 0.f};
#pragma unroll
    for (int m = 0; m < 2; ++m)
#pragma unroll
      for (int r = 0; r < 4; ++r) {
        int jl = 32 * jh + 16 * m + 4 * l4 + r;
        float wj = wtil[jl];
#pragma unroll
        for (int n = 0; n < 4; ++n) {
          float vv = fmaxf(acc[m][n][r] + hv[n], 0.f);
          part[n] = fmaf(wj, vv, part[n]);
        }
      }
#pragma unroll
    for (int n = 0; n < 4; ++n) {
      part[n] += __shfl_xor(part[n], 16);
      part[n] += __shfl_xor(part[n], 32);
    }
    if (l4 == 0) {
      f32x4 pv = {part[0], part[1], part[2], part[3]};
      *(f32x4*)&agg2[jh][hh * 64 + 4 * l15] = pv;
    }
  }
  __syncthreads();
  if (tid < 128)
    aggp[((size_t)blk * 4 + q) * 128 + tid] = agg2[0][tid] + agg2[1][tid];
}

// ---------------------------------------------------------------------------
// Kernel D: per node (8 per block): merge 4 partial softmax blocks ->
// agg; agg@Wm2+bm2; u = relu(h@Wo_src + .@Wo_dst + bo1); out = u@Wo2+bo2;
// res = h+out; LayerNorm; mask.
// ---------------------------------------------------------------------------
__global__ __launch_bounds__(256) void kernD(
    const float* __restrict__ hsrc, const int* __restrict__ vmask,
    const float* __restrict__ aggp, const float2* __restrict__ msbuf,
    const float* __restrict__ Wm2, const float* __restrict__ bm2,
    const float* __restrict__ Wo1, const float* __restrict__ bo1,
    const float* __restrict__ Wo2, const float* __restrict__ bo2,
    const float* __restrict__ gma, const float* __restrict__ bta,
    float* __restrict__ outp) {
  __shared__ float hL[8][128], xL[8][128], uL[8][128], rL[8][128];
  const int tid = threadIdx.x;
  const int col = tid & 127, g2 = tid >> 7;
  const int base = blockIdx.x * 8;
  for (int qq = 0; qq < 4; ++qq) {
    int g = qq * 2 + g2;
    int node = base + g;
    hL[g][col] = hsrc[(size_t)node * 128 + col];
    float xv = 0.f;
    if (vmask[node]) {
      float2 ms0 = msbuf[node * 4 + 0], ms1 = msbuf[node * 4 + 1];
      float2 ms2 = msbuf[node * 4 + 2], ms3 = msbuf[node * 4 + 3];
      float m = fmaxf(fmaxf(ms0.x, ms1.x), fmaxf(ms2.x, ms3.x));
      float w0 = __expf(ms0.x - m), w1 = __expf(ms1.x - m);
      float w2 = __expf(ms2.x - m), w3 = __expf(ms3.x - m);
      float den = w0 * ms0.y + w1 * ms1.y + w2 * ms2.y + w3 * ms3.y;
      size_t ab = (size_t)node * 4 * 128 + col;
      float num = w0 * aggp[ab] + w1 * aggp[ab + 128] + w2 * aggp[ab + 256] +
                  w3 * aggp[ab + 384];
      xv = num / den;
    }
    xL[g][col] = xv;
  }
  __syncthreads();
  float a4[4];
#pragma unroll
  for (int qq = 0; qq < 4; ++qq) a4[qq] = 0.f;
  for (int k = 0; k < 128; k += 4) {
    float w0 = Wm2[(k + 0) * 128 + col], w1 = Wm2[(k + 1) * 128 + col];
    float w2 = Wm2[(k + 2) * 128 + col], w3 = Wm2[(k + 3) * 128 + col];
#pragma unroll
    for (int qq = 0; qq < 4; ++qq) {
      const float4 xv = *(const float4*)&xL[g2 * 4 + qq][k];
      a4[qq] = fmaf(xv.x, w0, fmaf(xv.y, w1, fmaf(xv.z, w2, fmaf(xv.w, w3, a4[qq]))));
    }
  }
  {
    float bv = bm2[col];
#pragma unroll
    for (int qq = 0; qq < 4; ++qq) uL[g2 * 4 + qq][col] = a4[qq] + bv;
  }
  __syncthreads();
#pragma unroll
  for (int qq = 0; qq < 4; ++qq) a4[qq] = 0.f;
  for (int k = 0; k < 128; k += 4) {
    float w0 = Wo1[(k + 0) * 128 + col], w1 = Wo1[(k + 1) * 128 + col];
    float w2 = Wo1[(k + 2) * 128 + col], w3 = Wo1[(k + 3) * 128 + col];
#pragma unroll
    for (int qq = 0; qq < 4; ++qq) {
      const float4 xv = *(const float4*)&hL[g2 * 4 + qq][k];
      a4[qq] = fmaf(xv.x, w0, fmaf(xv.y, w1, fmaf(xv.z, w2, fmaf(xv.w, w3, a4[qq]))));
    }
  }
  for (int k = 0; k < 128; k += 4) {
    float w0 = Wo1[(128 + k + 0) * 128 + col], w1 = Wo1[(128 + k + 1) * 128 + col];
    float w2 = Wo1[(128 + k + 2) * 128 + col], w3 = Wo1[(128 + k + 3) * 128 + col];
#pragma unroll
    for (int qq = 0; qq < 4; ++qq) {
      const float4 xv = *(const float4*)&uL[g2 * 4 + qq][k];
      a4[qq] = fmaf(xv.x, w0, fmaf(xv.y, w1, fmaf(xv.z, w2, fmaf(xv.w, w3, a4[qq]))));
    }
  }
  {
    float bv = bo1[col];
#pragma unroll
    for (int qq = 0; qq < 4; ++qq) rL[g2 * 4 + qq][col] = fmaxf(a4[qq] + bv, 0.f);
  }
  __syncthreads();
#pragma unroll
  for (int qq = 0; qq < 4; ++qq) a4[qq] = 0.f;
  for (int k = 0; k < 128; k += 4) {
    float w0 = Wo2[(k + 0) * 128 + col], w1 = Wo2[(k + 1) * 128 + col];
    float w2 = Wo2[(k + 2) * 128 + col], w3 = Wo2[(k + 3) * 128 + col];
#pragma unroll
    for (int qq = 0; qq < 4; ++qq) {
      const float4 xv = *(const float4*)&rL[g2 * 4 + qq][k];
      a4[qq] = fmaf(xv.x, w0, fmaf(xv.y, w1, fmaf(xv.z, w2, fmaf(xv.w, w3, a4[qq]))));
    }
  }
  {
    float bv = bo2[col];
#pragma unroll
    for (int qq = 0; qq < 4; ++qq)
      xL[g2 * 4 + qq][col] = hL[g2 * 4 + qq][col] + a4[qq] + bv;
  }
  __syncthreads();
  const int wv = tid >> 6, ln = tid & 63;
  for (int s = 0; s < 2; ++s) {
    int g = wv * 2 + s;
    int node = base + g;
    float x0 = xL[g][ln], x1 = xL[g][ln + 64];
    float sm = x0 + x1;
#pragma unroll
    for (int o = 1; o < 64; o <<= 1) sm += __shfl_xor(sm, o);
    float mu = sm * (1.f / 128.f);
    float d0 = x0 - mu, d1 = x1 - mu;
    float vs = d0 * d0 + d1 * d1;
#pragma unroll
    for (int o = 1; o < 64; o <<= 1) vs += __shfl_xor(vs, o);
    float inv = rsqrtf(vs * (1.f / 128.f) + 1e-5f);
    int valid = vmask[node];
    float o0 = valid ? (d0 * inv * gma[ln] + bta[ln]) : 0.f;
    float o1 = valid ? (d1 * inv * gma[ln + 64] + bta[ln + 64]) : 0.f;
    outp[(size_t)node * 128 + ln] = o0;
    outp[(size_t)node * 128 + ln + 64] = o1;
  }
}

// ---------------------------------------------------------------------------
extern "C" void kernel_launch(void* const* d_in, const int* in_sizes, int n_in,
                              void* d_out, int out_size, void* d_ws, size_t ws_size,
                              hipStream_t stream) {
  const float* h_in = (const float*)d_in[0];
  const float* ef = (const float*)d_in[1];
  const int* vmask = (const int*)d_in[2];
  const float* We1 = (const float*)d_in[3];
  const float* be1 = (const float*)d_in[4];
  const float* We2 = (const float*)d_in[5];
  const float* be2 = (const float*)d_in[6];
  const float* Wa1 = (const float*)d_in[7];
  const float* ba1 = (const float*)d_in[8];
  const float* Wa2 = (const float*)d_in[9];
  const float* ba2 = (const float*)d_in[10];
  const float* Wm1 = (const float*)d_in[11];
  const float* bm1 = (const float*)d_in[12];
  const float* Wm2 = (const float*)d_in[13];
  const float* bm2 = (const float*)d_in[14];
  const float* Wo1 = (const float*)d_in[15];
  const float* bo1 = (const float*)d_in[16];
  const float* Wo2 = (const float*)d_in[17];
  const float* bo2 = (const float*)d_in[18];
  const float* gma = (const float*)d_in[19];
  const float* bta = (const float*)d_in[20];

  char* ws = (char*)d_ws;
  short* we1p = (short*)(ws + 0);                    // 8192 B
  short* weap = (short*)(ws + 8192);                 // 32768 B
  short* wemp = (short*)(ws + 40960);                // 32768 B
  float* bea = (float*)(ws + 73728);                 // 512 B
  float* bem = (float*)(ws + 74240);                 // 512 B
  int* compact = (int*)(ws + 74752);                 // 8192 B
  int* rmap = (int*)(ws + 82944);                    // 8192 B
  int* cnt = (int*)(ws + 91136);                     // 64 B
  float* asrcb = (float*)(ws + 91200);               // 1 MiB
  float* hmb = (float*)(ws + 91200 + 1048576);       // 1 MiB
  unsigned short* adst_bf = (unsigned short*)(ws + 91200 + 2097152);  // 512 KiB
  float* aggp = (float*)(ws + 91200 + 2621440);      // 4 MiB (2048 nodes x 4 x 128)
  float2* msbuf = (float2*)(ws + 91200 + 2621440 + 4194304);  // 64 KiB

  kernA<<<dim3(145), dim3(256), 0, stream>>>(We1, We2, be2, Wa1, ba1, Wm1, bm1,
                                             we1p, weap, wemp, bea, bem);
  kernA2<<<dim3(1), dim3(256), 0, stream>>>(vmask, compact, rmap, cnt);
  kernB<<<dim3(256), dim3(128), 0, stream>>>(h_in, Wa1, Wm1, bea, bem, asrcb,
                                             adst_bf, hmb);
  kernC<<<dim3(4096), dim3(256), 0, stream>>>(ef, vmask, compact, cnt, we1p, weap,
                                              wemp, asrcb, adst_bf, hmb, Wa2, be1,
                                              ba2, aggp, msbuf);
  kernD<<<dim3(256), dim3(256), 0, stream>>>(h_in, vmask, aggp, msbuf, Wm2, bm2,
                                             Wo1, bo1, Wo2, bo2, gma, bta,
                                             (float*)d_out);
}

// Round 5
// 105.572 us; speedup vs baseline: 3.2057x; 1.1396x over previous
//
#include <hip/hip_runtime.h>

// AGDN graph layer, fused. B=8, L=256, H=128, E=32.
// (see comments in previous rounds; this round adds j-compaction, fused
// pre-kernel, cheaper tanh via raw v_exp/v_rcp, and grid-coverage fix.)

typedef __attribute__((ext_vector_type(8))) short bhalf8;
typedef __attribute__((ext_vector_type(4))) float f32x4;

__device__ __forceinline__ short f2bf(float f) {
  union { float f; unsigned u; } v; v.f = f;
  unsigned r = (v.u + 0x7FFFu + ((v.u >> 16) & 1u)) >> 16;  // RNE
  return (short)r;
}
__device__ __forceinline__ unsigned cvt_pk(float lo, float hi) {
  unsigned r;
  asm("v_cvt_pk_bf16_f32 %0, %1, %2" : "=v"(r) : "v"(lo), "v"(hi));
  return r;
}
__device__ __forceinline__ float rawexp2(float x) {
  float r;
  asm("v_exp_f32 %0, %1" : "=v"(r) : "v"(x));
  return r;
}
__device__ __forceinline__ float rawrcp(float x) {
  float r;
  asm("v_rcp_f32 %0, %1" : "=v"(r) : "v"(x));
  return r;
}
__device__ __forceinline__ float bf2f(unsigned short x) {
  union { unsigned u; float f; } t; t.u = ((unsigned)x) << 16; return t.f;
}
__device__ __forceinline__ f32x4 mfma16(bhalf8 a, bhalf8 b, f32x4 c) {
  return __builtin_amdgcn_mfma_f32_16x16x32_bf16(a, b, c, 0, 0, 0);
}

// ---------------------------------------------------------------------------
// Fused pre-kernel: blocks 0..144 = weight packing; block 145 = compaction
// (+ per-batch bstart); blocks 146..401 = node GEMVs (NO bias add; bea/bem
// folded into kernC staging so all three parts are independent).
// ---------------------------------------------------------------------------
__global__ __launch_bounds__(256) void fusedPre(
    const float* __restrict__ hsrc, const int* __restrict__ vmask,
    const float* __restrict__ We1, const float* __restrict__ We2,
    const float* __restrict__ be2, const float* __restrict__ Wa1,
    const float* __restrict__ ba1, const float* __restrict__ Wm1,
    const float* __restrict__ bm1,
    short* __restrict__ we1p, short* __restrict__ weap, short* __restrict__ wemp,
    float* __restrict__ bea, float* __restrict__ bem,
    int* __restrict__ compact, int* __restrict__ bstart, int* __restrict__ cnt,
    float* __restrict__ asrcb, unsigned short* __restrict__ adst_bf,
    float* __restrict__ hmb) {
  __shared__ float shf[8][128];
  __shared__ int wsum[4];
  const int blk = blockIdx.x;
  const int tid = threadIdx.x;

  if (blk < 145) {  // ---------------- weight packing ----------------
    int u = blk * 256 + tid;
    if (u < 4096) {
      int e = u & 7, lane = (u >> 3) & 63, nt = u >> 9;
      int k = 8 * (lane >> 4) + e, n = 16 * nt + (lane & 15);
      we1p[u] = f2bf(We1[k * 128 + n]);
    } else if (u < 20480) {               // Wea packed, permuted cols
      int v = u - 4096;
      int e = v & 7, lane = (v >> 3) & 63, nt = (v >> 9) & 7, ks = v >> 12;
      int k = 32 * ks + 8 * (lane >> 4) + e;
      int co = 64 * (nt >> 2) + 4 * (lane & 15) + (nt & 3);
      float a0 = 0.f, a1 = 0.f, a2 = 0.f, a3 = 0.f;
      for (int c = 0; c < 128; c += 4) {
        const float4 w4 = *(const float4*)&We2[k * 128 + c];
        a0 = fmaf(w4.x, Wa1[(256 + c + 0) * 128 + co], a0);
        a1 = fmaf(w4.y, Wa1[(256 + c + 1) * 128 + co], a1);
        a2 = fmaf(w4.z, Wa1[(256 + c + 2) * 128 + co], a2);
        a3 = fmaf(w4.w, Wa1[(256 + c + 3) * 128 + co], a3);
      }
      weap[v] = f2bf((a0 + a1) + (a2 + a3));
    } else if (u < 36864) {               // Wem packed, permuted cols
      int v = u - 20480;
      int e = v & 7, lane = (v >> 3) & 63, nt = (v >> 9) & 7, ks = v >> 12;
      int k = 32 * ks + 8 * (lane >> 4) + e;
      int co = 64 * (nt >> 2) + 4 * (lane & 15) + (nt & 3);
      float a0 = 0.f, a1 = 0.f, a2 = 0.f, a3 = 0.f;
      for (int c = 0; c < 128; c += 4) {
        const float4 w4 = *(const float4*)&We2[k * 128 + c];
        a0 = fmaf(w4.x, Wm1[(128 + c + 0) * 128 + co], a0);
        a1 = fmaf(w4.y, Wm1[(128 + c + 1) * 128 + co], a1);
        a2 = fmaf(w4.z, Wm1[(128 + c + 2) * 128 + co], a2);
        a3 = fmaf(w4.w, Wm1[(128 + c + 3) * 128 + co], a3);
      }
      wemp[v] = f2bf((a0 + a1) + (a2 + a3));
    } else if (u < 36992) {
      int hc = u - 36864;
      float acc = ba1[hc];
      for (int c = 0; c < 128; ++c)
        acc = fmaf(be2[c], Wa1[(256 + c) * 128 + hc], acc);
      bea[hc] = acc;
    } else if (u < 37120) {
      int hc = u - 36992;
      float acc = bm1[hc];
      for (int c = 0; c < 128; ++c)
        acc = fmaf(be2[c], Wm1[(128 + c) * 128 + hc], acc);
      bem[hc] = acc;
    }
  } else if (blk == 145) {  // ------------- compaction -------------
    int loc[8], c = 0;
#pragma unroll
    for (int q = 0; q < 8; ++q) {
      int v = vmask[tid * 8 + q] != 0;
      loc[q] = v;
      c += v;
    }
    const int l = tid & 63, w = tid >> 6;
    int pre = c;
#pragma unroll
    for (int o = 1; o < 64; o <<= 1) {
      int t = __shfl_up(pre, o);
      if (l >= o) pre += t;
    }
    if (l == 63) wsum[w] = pre;
    __syncthreads();
    int base = 0;
    for (int q = 0; q < w; ++q) base += wsum[q];
    int off = base + pre - c;
    if ((tid & 31) == 0) bstart[tid >> 5] = off;
#pragma unroll
    for (int q = 0; q < 8; ++q)
      if (loc[q]) compact[off++] = tid * 8 + q;
    if (tid == 255) { cnt[0] = off; bstart[8] = off; }
  } else {  // ---------------- node GEMVs ----------------
    const int base = (blk - 146) * 8;
    const int col = tid & 127, half = tid >> 7;
#pragma unroll
    for (int g = 0; g < 4; ++g)
      shf[half * 4 + g][col] = hsrc[(size_t)(base + half * 4 + g) * 128 + col];
    __syncthreads();
    float aS[4], aD[4], aM[4];
#pragma unroll
    for (int g = 0; g < 4; ++g) { aS[g] = 0.f; aD[g] = 0.f; aM[g] = 0.f; }
    for (int k = 0; k < 128; k += 4) {
      float s0 = Wa1[(k + 0) * 128 + col], s1 = Wa1[(k + 1) * 128 + col];
      float s2 = Wa1[(k + 2) * 128 + col], s3 = Wa1[(k + 3) * 128 + col];
      float d0 = Wa1[(128 + k + 0) * 128 + col], d1 = Wa1[(128 + k + 1) * 128 + col];
      float d2 = Wa1[(128 + k + 2) * 128 + col], d3 = Wa1[(128 + k + 3) * 128 + col];
      float m0 = Wm1[(k + 0) * 128 + col], m1 = Wm1[(k + 1) * 128 + col];
      float m2 = Wm1[(k + 2) * 128 + col], m3 = Wm1[(k + 3) * 128 + col];
#pragma unroll
      for (int g = 0; g < 4; ++g) {
        const float4 hv = *(const float4*)&shf[half * 4 + g][k];
        aS[g] = fmaf(hv.x, s0, fmaf(hv.y, s1, fmaf(hv.z, s2, fmaf(hv.w, s3, aS[g]))));
        aD[g] = fmaf(hv.x, d0, fmaf(hv.y, d1, fmaf(hv.z, d2, fmaf(hv.w, d3, aD[g]))));
        aM[g] = fmaf(hv.x, m0, fmaf(hv.y, m1, fmaf(hv.z, m2, fmaf(hv.w, m3, aM[g]))));
      }
    }
#pragma unroll
    for (int g = 0; g < 4; ++g) {
      size_t o = (size_t)(base + half * 4 + g) * 128 + col;
      asrcb[o] = aS[g];
      adst_bf[o] = (unsigned short)f2bf(aD[g]);
      hmb[o] = aM[g];
    }
  }
}

// ---------------------------------------------------------------------------
// Kernel C: one block per (valid node rank v, chunk q of 64 VALID j's).
// ---------------------------------------------------------------------------
__global__ __launch_bounds__(256) void kernC(
    const float* __restrict__ ef, const int* __restrict__ compact,
    const int* __restrict__ bstart, const int* __restrict__ cnt,
    const short* __restrict__ we1p, const short* __restrict__ weap,
    const short* __restrict__ wemp, const float* __restrict__ asrcb,
    const unsigned short* __restrict__ adst_bf, const float* __restrict__ hmb,
    const float* __restrict__ wa2, const float* __restrict__ be1,
    const float* __restrict__ ba2, const float* __restrict__ bea,
    const float* __restrict__ bem, float* __restrict__ aggp,
    float2* __restrict__ msbuf) {
  const int nv = cnt[0];
  const int v = blockIdx.x >> 2;
  if (v >= nv) return;
  const int q = blockIdx.x & 3;
  const int blk = compact[v];
  const int b = blk >> 8;
  const int jb0 = bstart[b];
  const int nb = bstart[b + 1] - jb0;
  const int tid = threadIdx.x;

  if (q * 64 >= nb) {  // unused chunk: deterministic zero-fill for kernD merge
    if (tid < 128) aggp[((size_t)blk * 4 + q) * 128 + tid] = 0.f;
    if (tid == 0) msbuf[blk * 4 + q] = make_float2(-1e30f, 0.f);
    return;
  }

  __shared__ short Tl[64 * 128];                  // 16KB, XOR-swizzled rows
  __shared__ float att2[2][64];
  __shared__ float wtil[64];
  __shared__ __align__(16) float asr_s[128], hm_s[128], wa2_s[128];
  __shared__ float be1_s[128];
  __shared__ __align__(16) float agg2[2][128];

  const int w = tid >> 6, l = tid & 63;
  const int l15 = l & 15, l4 = l >> 4;
  const int jh = w >> 1, hh = w & 1;

  // valid-j row indices for this lane's T rows, then EF loads (early issue)
  int jrow[2];
  float4 f0[2], f1[2];
#pragma unroll
  for (int m = 0; m < 2; ++m) {
    int idx = q * 64 + 32 * jh + 16 * m + l15;
    jrow[m] = compact[jb0 + (idx < nb ? idx : nb - 1)] & 255;
    const float* p = ef + (((size_t)blk * 256 + jrow[m]) * 32 + 8 * l4);
    f0[m] = *(const float4*)p;
    f1[m] = *(const float4*)(p + 4);
  }

  if (tid < 128) {
    asr_s[tid] = asrcb[(size_t)blk * 128 + tid] + bea[tid];
    hm_s[tid] = hmb[(size_t)blk * 128 + tid] + bem[tid];
    wa2_s[tid] = wa2[tid];
    be1_s[tid] = be1[tid];
  }
  __syncthreads();

  const float ba2v = ba2[0];
  const float RS = 0.08838834764831845f;          // 1/sqrt(128)
  const f32x4 vz = {0.f, 0.f, 0.f, 0.f};
  const f32x4 asv = *(const f32x4*)&asr_s[hh * 64 + 4 * l15];
  const f32x4 wav = *(const f32x4*)&wa2_s[hh * 64 + 4 * l15];
  float whalf = wav[0] + wav[1] + wav[2] + wav[3];
  whalf += __shfl_xor(whalf, 1);
  whalf += __shfl_xor(whalf, 2);
  whalf += __shfl_xor(whalf, 4);
  whalf += __shfl_xor(whalf, 8);

  // ---- T = relu(EF @ We1 + be1) -> Tl (swizzled) ----
  {
    f32x4 acc[2][4];
#pragma unroll
    for (int m = 0; m < 2; ++m)
#pragma unroll
      for (int n = 0; n < 4; ++n) acc[m][n] = vz;
#pragma unroll
    for (int m = 0; m < 2; ++m) {
      union { bhalf8 v8; unsigned u[4]; } a;
      a.u[0] = cvt_pk(f0[m].x, f0[m].y);
      a.u[1] = cvt_pk(f0[m].z, f0[m].w);
      a.u[2] = cvt_pk(f1[m].x, f1[m].y);
      a.u[3] = cvt_pk(f1[m].z, f1[m].w);
#pragma unroll
      for (int n = 0; n < 4; ++n) {
        bhalf8 bfr = *(const bhalf8*)(we1p + (size_t)((hh * 4 + n) * 64 + l) * 8);
        acc[m][n] = mfma16(a.v8, bfr, acc[m][n]);
      }
    }
#pragma unroll
    for (int m = 0; m < 2; ++m)
#pragma unroll
      for (int n = 0; n < 4; ++n) {
        int hc = hh * 64 + 16 * n + l15;
        float bias = be1_s[hc];
#pragma unroll
        for (int r = 0; r < 4; ++r) {
          int jl = 32 * jh + 16 * m + 4 * l4 + r;
          float vv = fmaxf(acc[m][n][r] + bias, 0.f);
          int byte = (jl * 256 + 2 * hc) ^ ((jl & 7) << 4);
          *(short*)((char*)Tl + byte) = (short)(cvt_pk(vv, vv) & 0xffff);
        }
      }
  }
  __syncthreads();

  // ---- attention logits: EA = T @ Wea ----
  {
    ushort4 adp[2][4];
#pragma unroll
    for (int m = 0; m < 2; ++m)
#pragma unroll
      for (int r = 0; r < 4; ++r) {
        int idx = q * 64 + 32 * jh + 16 * m + 4 * l4 + r;
        int jg = compact[jb0 + (idx < nb ? idx : nb - 1)] & 255;
        adp[m][r] = *(const ushort4*)(adst_bf + (size_t)(b * 256 + jg) * 128 +
                                      hh * 64 + 4 * l15);
      }
    f32x4 acc[2][4];
#pragma unroll
    for (int m = 0; m < 2; ++m)
#pragma unroll
      for (int n = 0; n < 4; ++n) acc[m][n] = vz;
#pragma unroll
    for (int ks = 0; ks < 4; ++ks) {
      bhalf8 af[2];
#pragma unroll
      for (int m = 0; m < 2; ++m) {
        int jl = 32 * jh + 16 * m + l15;
        int byte = (jl * 256 + ks * 64 + 16 * l4) ^ ((jl & 7) << 4);
        af[m] = *(const bhalf8*)((const char*)Tl + byte);
      }
#pragma unroll
      for (int n = 0; n < 4; ++n) {
        bhalf8 bf2 = *(const bhalf8*)(weap + (size_t)((ks * 8 + hh * 4 + n) * 64 + l) * 8);
#pragma unroll
        for (int m = 0; m < 2; ++m) acc[m][n] = mfma16(af[m], bf2, acc[m][n]);
      }
    }
    // sum_h wa2*tanh(x) = whalf - 2*sum_h wa2 * rcp(exp2(2log2e*x) + 1)
#pragma unroll
    for (int m = 0; m < 2; ++m)
#pragma unroll
      for (int r = 0; r < 4; ++r) {
        float racc = 0.f;
        float adv[4] = {bf2f(adp[m][r].x), bf2f(adp[m][r].y),
                        bf2f(adp[m][r].z), bf2f(adp[m][r].w)};
#pragma unroll
        for (int n = 0; n < 4; ++n) {
          float x = acc[m][n][r] + asv[n] + adv[n];
          float e = rawexp2(x * 2.885390082f);    // e^(2x)
          racc = fmaf(wav[n], rawrcp(e + 1.f), racc);
        }
        racc += __shfl_xor(racc, 1);
        racc += __shfl_xor(racc, 2);
        racc += __shfl_xor(racc, 4);
        racc += __shfl_xor(racc, 8);
        if (l15 == 0)
          att2[hh][32 * jh + 16 * m + 4 * l4 + r] = whalf - 2.f * racc;
      }
  }
  __syncthreads();

  // ---- partial softmax over this chunk's 64 slots (wave 0) ----
  if (w == 0) {
    int idx = q * 64 + l;
    float s = (idx < nb) ? (att2[0][l] + att2[1][l] + ba2v) * RS : -1e30f;
    float mx = s;
#pragma unroll
    for (int o = 1; o < 64; o <<= 1) mx = fmaxf(mx, __shfl_xor(mx, o));
    float e = __expf(s - mx);
    wtil[l] = e;
    float sm = e;
#pragma unroll
    for (int o = 1; o < 64; o <<= 1) sm += __shfl_xor(sm, o);
    if (l == 0) msbuf[blk * 4 + q] = make_float2(mx, sm);
  }
  __syncthreads();

  // ---- message: EM = T @ Wem ; weighted relu-agg (unnormalized) ----
  {
    const f32x4 hv = *(const f32x4*)&hm_s[hh * 64 + 4 * l15];
    f32x4 acc[2][4];
#pragma unroll
    for (int m = 0; m < 2; ++m)
#pragma unroll
      for (int n = 0; n < 4; ++n) acc[m][n] = vz;
#pragma unroll
    for (int ks = 0; ks < 4; ++ks) {
      bhalf8 af[2];
#pragma unroll
      for (int m = 0; m < 2; ++m) {
        int jl = 32 * jh + 16 * m + l15;
        int byte = (jl * 256 + ks * 64 + 16 * l4) ^ ((jl & 7) << 4);
        af[m] = *(const bhalf8*)((const char*)Tl + byte);
      }
#pragma unroll
      for (int n = 0; n < 4; ++n) {
        bhalf8 bf2 = *(const bhalf8*)(wemp + (size_t)((ks * 8 + hh * 4 + n) * 64 + l) * 8);
#pragma unroll
        for (int m = 0; m < 2; ++m) acc[m][n] = mfma16(af[m], bf2, acc[m][n]);
      }
    }
    float part[4] = {0.f, 0.f, 0.f, 0.f};
#pragma unroll
    for (int m = 0; m < 2; ++m)
#pragma unroll
      for (int r = 0; r < 4; ++r) {
        int jl = 32 * jh + 16 * m + 4 * l4 + r;
        float wj = wtil[jl];
#pragma unroll
        for (int n = 0; n < 4; ++n) {
          float vv = fmaxf(acc[m][n][r] + hv[n], 0.f);
          part[n] = fmaf(wj, vv, part[n]);
        }
      }
#pragma unroll
    for (int n = 0; n < 4; ++n) {
      part[n] += __shfl_xor(part[n], 16);
      part[n] += __shfl_xor(part[n], 32);
    }
    if (l4 == 0) {
      f32x4 pv = {part[0], part[1], part[2], part[3]};
      *(f32x4*)&agg2[jh][hh * 64 + 4 * l15] = pv;
    }
  }
  __syncthreads();
  if (tid < 128)
    aggp[((size_t)blk * 4 + q) * 128 + tid] = agg2[0][tid] + agg2[1][tid];
}

// ---------------------------------------------------------------------------
// Kernel D: merge partial chunks; agg@Wm2; out-MLP; residual; LayerNorm; mask.
// ---------------------------------------------------------------------------
__global__ __launch_bounds__(256) void kernD(
    const float* __restrict__ hsrc, const int* __restrict__ vmask,
    const float* __restrict__ aggp, const float2* __restrict__ msbuf,
    const float* __restrict__ Wm2, const float* __restrict__ bm2,
    const float* __restrict__ Wo1, const float* __restrict__ bo1,
    const float* __restrict__ Wo2, const float* __restrict__ bo2,
    const float* __restrict__ gma, const float* __restrict__ bta,
    float* __restrict__ outp) {
  __shared__ float hL[8][128], xL[8][128], uL[8][128], rL[8][128];
  const int tid = threadIdx.x;
  const int col = tid & 127, g2 = tid >> 7;
  const int base = blockIdx.x * 8;
  for (int qq = 0; qq < 4; ++qq) {
    int g = qq * 2 + g2;
    int node = base + g;
    hL[g][col] = hsrc[(size_t)node * 128 + col];
    float xv = 0.f;
    if (vmask[node]) {
      float2 ms0 = msbuf[node * 4 + 0], ms1 = msbuf[node * 4 + 1];
      float2 ms2 = msbuf[node * 4 + 2], ms3 = msbuf[node * 4 + 3];
      float m = fmaxf(fmaxf(ms0.x, ms1.x), fmaxf(ms2.x, ms3.x));
      float w0 = __expf(ms0.x - m), w1 = __expf(ms1.x - m);
      float w2 = __expf(ms2.x - m), w3 = __expf(ms3.x - m);
      float den = w0 * ms0.y + w1 * ms1.y + w2 * ms2.y + w3 * ms3.y;
      size_t ab = (size_t)node * 4 * 128 + col;
      float num = w0 * aggp[ab] + w1 * aggp[ab + 128] + w2 * aggp[ab + 256] +
                  w3 * aggp[ab + 384];
      xv = num / den;
    }
    xL[g][col] = xv;
  }
  __syncthreads();
  float a4[4];
#pragma unroll
  for (int qq = 0; qq < 4; ++qq) a4[qq] = 0.f;
  for (int k = 0; k < 128; k += 4) {
    float w0 = Wm2[(k + 0) * 128 + col], w1 = Wm2[(k + 1) * 128 + col];
    float w2 = Wm2[(k + 2) * 128 + col], w3 = Wm2[(k + 3) * 128 + col];
#pragma unroll
    for (int qq = 0; qq < 4; ++qq) {
      const float4 xv = *(const float4*)&xL[g2 * 4 + qq][k];
      a4[qq] = fmaf(xv.x, w0, fmaf(xv.y, w1, fmaf(xv.z, w2, fmaf(xv.w, w3, a4[qq]))));
    }
  }
  {
    float bv = bm2[col];
#pragma unroll
    for (int qq = 0; qq < 4; ++qq) uL[g2 * 4 + qq][col] = a4[qq] + bv;
  }
  __syncthreads();
#pragma unroll
  for (int qq = 0; qq < 4; ++qq) a4[qq] = 0.f;
  for (int k = 0; k < 128; k += 4) {
    float w0 = Wo1[(k + 0) * 128 + col], w1 = Wo1[(k + 1) * 128 + col];
    float w2 = Wo1[(k + 2) * 128 + col], w3 = Wo1[(k + 3) * 128 + col];
#pragma unroll
    for (int qq = 0; qq < 4; ++qq) {
      const float4 xv = *(const float4*)&hL[g2 * 4 + qq][k];
      a4[qq] = fmaf(xv.x, w0, fmaf(xv.y, w1, fmaf(xv.z, w2, fmaf(xv.w, w3, a4[qq]))));
    }
  }
  for (int k = 0; k < 128; k += 4) {
    float w0 = Wo1[(128 + k + 0) * 128 + col], w1 = Wo1[(128 + k + 1) * 128 + col];
    float w2 = Wo1[(128 + k + 2) * 128 + col], w3 = Wo1[(128 + k + 3) * 128 + col];
#pragma unroll
    for (int qq = 0; qq < 4; ++qq) {
      const float4 xv = *(const float4*)&uL[g2 * 4 + qq][k];
      a4[qq] = fmaf(xv.x, w0, fmaf(xv.y, w1, fmaf(xv.z, w2, fmaf(xv.w, w3, a4[qq]))));
    }
  }
  {
    float bv = bo1[col];
#pragma unroll
    for (int qq = 0; qq < 4; ++qq) rL[g2 * 4 + qq][col] = fmaxf(a4[qq] + bv, 0.f);
  }
  __syncthreads();
#pragma unroll
  for (int qq = 0; qq < 4; ++qq) a4[qq] = 0.f;
  for (int k = 0; k < 128; k += 4) {
    float w0 = Wo2[(k + 0) * 128 + col], w1 = Wo2[(k + 1) * 128 + col];
    float w2 = Wo2[(k + 2) * 128 + col], w3 = Wo2[(k + 3) * 128 + col];
#pragma unroll
    for (int qq = 0; qq < 4; ++qq) {
      const float4 xv = *(const float4*)&rL[g2 * 4 + qq][k];
      a4[qq] = fmaf(xv.x, w0, fmaf(xv.y, w1, fmaf(xv.z, w2, fmaf(xv.w, w3, a4[qq]))));
    }
  }
  {
    float bv = bo2[col];
#pragma unroll
    for (int qq = 0; qq < 4; ++qq)
      xL[g2 * 4 + qq][col] = hL[g2 * 4 + qq][col] + a4[qq] + bv;
  }
  __syncthreads();
  const int wv = tid >> 6, ln = tid & 63;
  for (int s = 0; s < 2; ++s) {
    int g = wv * 2 + s;
    int node = base + g;
    float x0 = xL[g][ln], x1 = xL[g][ln + 64];
    float sm = x0 + x1;
#pragma unroll
    for (int o = 1; o < 64; o <<= 1) sm += __shfl_xor(sm, o);
    float mu = sm * (1.f / 128.f);
    float d0 = x0 - mu, d1 = x1 - mu;
    float vs = d0 * d0 + d1 * d1;
#pragma unroll
    for (int o = 1; o < 64; o <<= 1) vs += __shfl_xor(vs, o);
    float inv = rsqrtf(vs * (1.f / 128.f) + 1e-5f);
    int valid = vmask[node];
    float o0 = valid ? (d0 * inv * gma[ln] + bta[ln]) : 0.f;
    float o1 = valid ? (d1 * inv * gma[ln + 64] + bta[ln + 64]) : 0.f;
    outp[(size_t)node * 128 + ln] = o0;
    outp[(size_t)node * 128 + ln + 64] = o1;
  }
}

// ---------------------------------------------------------------------------
extern "C" void kernel_launch(void* const* d_in, const int* in_sizes, int n_in,
                              void* d_out, int out_size, void* d_ws, size_t ws_size,
                              hipStream_t stream) {
  const float* h_in = (const float*)d_in[0];
  const float* ef = (const float*)d_in[1];
  const int* vmask = (const int*)d_in[2];
  const float* We1 = (const float*)d_in[3];
  const float* be1 = (const float*)d_in[4];
  const float* We2 = (const float*)d_in[5];
  const float* be2 = (const float*)d_in[6];
  const float* Wa1 = (const float*)d_in[7];
  const float* ba1 = (const float*)d_in[8];
  const float* Wa2 = (const float*)d_in[9];
  const float* ba2 = (const float*)d_in[10];
  const float* Wm1 = (const float*)d_in[11];
  const float* bm1 = (const float*)d_in[12];
  const float* Wm2 = (const float*)d_in[13];
  const float* bm2 = (const float*)d_in[14];
  const float* Wo1 = (const float*)d_in[15];
  const float* bo1 = (const float*)d_in[16];
  const float* Wo2 = (const float*)d_in[17];
  const float* bo2 = (const float*)d_in[18];
  const float* gma = (const float*)d_in[19];
  const float* bta = (const float*)d_in[20];

  char* ws = (char*)d_ws;
  short* we1p = (short*)(ws + 0);                    // 8192 B
  short* weap = (short*)(ws + 8192);                 // 32768 B
  short* wemp = (short*)(ws + 40960);                // 32768 B
  float* bea = (float*)(ws + 73728);                 // 512 B
  float* bem = (float*)(ws + 74240);                 // 512 B
  int* compact = (int*)(ws + 74752);                 // 8192 B
  int* bstart = (int*)(ws + 82944);                  // 64 B (9 ints)
  int* cnt = (int*)(ws + 83072);                     // 64 B
  float* asrcb = (float*)(ws + 83136);               // 1 MiB
  float* hmb = (float*)(ws + 83136 + 1048576);       // 1 MiB
  unsigned short* adst_bf = (unsigned short*)(ws + 83136 + 2097152);  // 512 KiB
  float* aggp = (float*)(ws + 83136 + 2621440);      // 4 MiB
  float2* msbuf = (float2*)(ws + 83136 + 2621440 + 4194304);  // 64 KiB

  fusedPre<<<dim3(402), dim3(256), 0, stream>>>(
      h_in, vmask, We1, We2, be2, Wa1, ba1, Wm1, bm1, we1p, weap, wemp, bea,
      bem, compact, bstart, cnt, asrcb, adst_bf, hmb);
  kernC<<<dim3(8192), dim3(256), 0, stream>>>(ef, compact, bstart, cnt, we1p,
                                              weap, wemp, asrcb, adst_bf, hmb,
                                              Wa2, be1, ba2, bea, bem, aggp,
                                              msbuf);
  kernD<<<dim3(256), dim3(256), 0, stream>>>(h_in, vmask, aggp, msbuf, Wm2, bm2,
                                             Wo1, bo1, Wo2, bo2, gma, bta,
                                             (float*)d_out);
}

// Round 6
// 83.697 us; speedup vs baseline: 4.0435x; 1.2614x over previous
//
#include <hip/hip_runtime.h>

// AGDN graph layer, fused. B=8, L=256, H=128, E=32.
//  - edge_h never materialized: Wea = We2@Wa_edge, Wem = We2@Wm_edge precomputed.
//  - Wm2 hoisted out of the pair loop (softmax weights sum to 1).
//  - j-compaction: only valid j's processed (order-preserving per-batch slices).
//  - permuted h_out cols -> all per-lane epilogue accesses are contiguous.
//  - partial softmax per 64-j chunk, merged in kernD.
//  - R6: kernD rewritten -- 1024 threads (col x node), one output elem/thread,
//    unrolled k-loops, wave-level LayerNorm. Round-5 kernD was 1 wave/SIMD with
//    serial dependent loads (VALUBusy 5%, 56 GB/s) = latency-bound at 68us.

typedef __attribute__((ext_vector_type(8))) short bhalf8;
typedef __attribute__((ext_vector_type(4))) float f32x4;

__device__ __forceinline__ short f2bf(float f) {
  union { float f; unsigned u; } v; v.f = f;
  unsigned r = (v.u + 0x7FFFu + ((v.u >> 16) & 1u)) >> 16;  // RNE
  return (short)r;
}
__device__ __forceinline__ unsigned cvt_pk(float lo, float hi) {
  unsigned r;
  asm("v_cvt_pk_bf16_f32 %0, %1, %2" : "=v"(r) : "v"(lo), "v"(hi));
  return r;
}
__device__ __forceinline__ float rawexp2(float x) {
  float r;
  asm("v_exp_f32 %0, %1" : "=v"(r) : "v"(x));
  return r;
}
__device__ __forceinline__ float rawrcp(float x) {
  float r;
  asm("v_rcp_f32 %0, %1" : "=v"(r) : "v"(x));
  return r;
}
__device__ __forceinline__ float bf2f(unsigned short x) {
  union { unsigned u; float f; } t; t.u = ((unsigned)x) << 16; return t.f;
}
__device__ __forceinline__ f32x4 mfma16(bhalf8 a, bhalf8 b, f32x4 c) {
  return __builtin_amdgcn_mfma_f32_16x16x32_bf16(a, b, c, 0, 0, 0);
}

// ---------------------------------------------------------------------------
// Fused pre-kernel: blocks 0..144 = weight packing; block 145 = compaction
// (+ per-batch bstart); blocks 146..401 = node GEMVs (NO bias add; bea/bem
// folded into kernC staging so all three parts are independent).
// ---------------------------------------------------------------------------
__global__ __launch_bounds__(256) void fusedPre(
    const float* __restrict__ hsrc, const int* __restrict__ vmask,
    const float* __restrict__ We1, const float* __restrict__ We2,
    const float* __restrict__ be2, const float* __restrict__ Wa1,
    const float* __restrict__ ba1, const float* __restrict__ Wm1,
    const float* __restrict__ bm1,
    short* __restrict__ we1p, short* __restrict__ weap, short* __restrict__ wemp,
    float* __restrict__ bea, float* __restrict__ bem,
    int* __restrict__ compact, int* __restrict__ bstart, int* __restrict__ cnt,
    float* __restrict__ asrcb, unsigned short* __restrict__ adst_bf,
    float* __restrict__ hmb) {
  __shared__ float shf[8][128];
  __shared__ int wsum[4];
  const int blk = blockIdx.x;
  const int tid = threadIdx.x;

  if (blk < 145) {  // ---------------- weight packing ----------------
    int u = blk * 256 + tid;
    if (u < 4096) {
      int e = u & 7, lane = (u >> 3) & 63, nt = u >> 9;
      int k = 8 * (lane >> 4) + e, n = 16 * nt + (lane & 15);
      we1p[u] = f2bf(We1[k * 128 + n]);
    } else if (u < 20480) {               // Wea packed, permuted cols
      int v = u - 4096;
      int e = v & 7, lane = (v >> 3) & 63, nt = (v >> 9) & 7, ks = v >> 12;
      int k = 32 * ks + 8 * (lane >> 4) + e;
      int co = 64 * (nt >> 2) + 4 * (lane & 15) + (nt & 3);
      float a0 = 0.f, a1 = 0.f, a2 = 0.f, a3 = 0.f;
      for (int c = 0; c < 128; c += 4) {
        const float4 w4 = *(const float4*)&We2[k * 128 + c];
        a0 = fmaf(w4.x, Wa1[(256 + c + 0) * 128 + co], a0);
        a1 = fmaf(w4.y, Wa1[(256 + c + 1) * 128 + co], a1);
        a2 = fmaf(w4.z, Wa1[(256 + c + 2) * 128 + co], a2);
        a3 = fmaf(w4.w, Wa1[(256 + c + 3) * 128 + co], a3);
      }
      weap[v] = f2bf((a0 + a1) + (a2 + a3));
    } else if (u < 36864) {               // Wem packed, permuted cols
      int v = u - 20480;
      int e = v & 7, lane = (v >> 3) & 63, nt = (v >> 9) & 7, ks = v >> 12;
      int k = 32 * ks + 8 * (lane >> 4) + e;
      int co = 64 * (nt >> 2) + 4 * (lane & 15) + (nt & 3);
      float a0 = 0.f, a1 = 0.f, a2 = 0.f, a3 = 0.f;
      for (int c = 0; c < 128; c += 4) {
        const float4 w4 = *(const float4*)&We2[k * 128 + c];
        a0 = fmaf(w4.x, Wm1[(128 + c + 0) * 128 + co], a0);
        a1 = fmaf(w4.y, Wm1[(128 + c + 1) * 128 + co], a1);
        a2 = fmaf(w4.z, Wm1[(128 + c + 2) * 128 + co], a2);
        a3 = fmaf(w4.w, Wm1[(128 + c + 3) * 128 + co], a3);
      }
      wemp[v] = f2bf((a0 + a1) + (a2 + a3));
    } else if (u < 36992) {
      int hc = u - 36864;
      float acc = ba1[hc];
      for (int c = 0; c < 128; ++c)
        acc = fmaf(be2[c], Wa1[(256 + c) * 128 + hc], acc);
      bea[hc] = acc;
    } else if (u < 37120) {
      int hc = u - 36992;
      float acc = bm1[hc];
      for (int c = 0; c < 128; ++c)
        acc = fmaf(be2[c], Wm1[(128 + c) * 128 + hc], acc);
      bem[hc] = acc;
    }
  } else if (blk == 145) {  // ------------- compaction -------------
    int loc[8], c = 0;
#pragma unroll
    for (int q = 0; q < 8; ++q) {
      int v = vmask[tid * 8 + q] != 0;
      loc[q] = v;
      c += v;
    }
    const int l = tid & 63, w = tid >> 6;
    int pre = c;
#pragma unroll
    for (int o = 1; o < 64; o <<= 1) {
      int t = __shfl_up(pre, o);
      if (l >= o) pre += t;
    }
    if (l == 63) wsum[w] = pre;
    __syncthreads();
    int base = 0;
    for (int q = 0; q < w; ++q) base += wsum[q];
    int off = base + pre - c;
    if ((tid & 31) == 0) bstart[tid >> 5] = off;
#pragma unroll
    for (int q = 0; q < 8; ++q)
      if (loc[q]) compact[off++] = tid * 8 + q;
    if (tid == 255) { cnt[0] = off; bstart[8] = off; }
  } else {  // ---------------- node GEMVs ----------------
    const int base = (blk - 146) * 8;
    const int col = tid & 127, half = tid >> 7;
#pragma unroll
    for (int g = 0; g < 4; ++g)
      shf[half * 4 + g][col] = hsrc[(size_t)(base + half * 4 + g) * 128 + col];
    __syncthreads();
    float aS[4], aD[4], aM[4];
#pragma unroll
    for (int g = 0; g < 4; ++g) { aS[g] = 0.f; aD[g] = 0.f; aM[g] = 0.f; }
    for (int k = 0; k < 128; k += 4) {
      float s0 = Wa1[(k + 0) * 128 + col], s1 = Wa1[(k + 1) * 128 + col];
      float s2 = Wa1[(k + 2) * 128 + col], s3 = Wa1[(k + 3) * 128 + col];
      float d0 = Wa1[(128 + k + 0) * 128 + col], d1 = Wa1[(128 + k + 1) * 128 + col];
      float d2 = Wa1[(128 + k + 2) * 128 + col], d3 = Wa1[(128 + k + 3) * 128 + col];
      float m0 = Wm1[(k + 0) * 128 + col], m1 = Wm1[(k + 1) * 128 + col];
      float m2 = Wm1[(k + 2) * 128 + col], m3 = Wm1[(k + 3) * 128 + col];
#pragma unroll
      for (int g = 0; g < 4; ++g) {
        const float4 hv = *(const float4*)&shf[half * 4 + g][k];
        aS[g] = fmaf(hv.x, s0, fmaf(hv.y, s1, fmaf(hv.z, s2, fmaf(hv.w, s3, aS[g]))));
        aD[g] = fmaf(hv.x, d0, fmaf(hv.y, d1, fmaf(hv.z, d2, fmaf(hv.w, d3, aD[g]))));
        aM[g] = fmaf(hv.x, m0, fmaf(hv.y, m1, fmaf(hv.z, m2, fmaf(hv.w, m3, aM[g]))));
      }
    }
#pragma unroll
    for (int g = 0; g < 4; ++g) {
      size_t o = (size_t)(base + half * 4 + g) * 128 + col;
      asrcb[o] = aS[g];
      adst_bf[o] = (unsigned short)f2bf(aD[g]);
      hmb[o] = aM[g];
    }
  }
}

// ---------------------------------------------------------------------------
// Kernel C: one block per (valid node rank v, chunk q of 64 VALID j's).
// ---------------------------------------------------------------------------
__global__ __launch_bounds__(256) void kernC(
    const float* __restrict__ ef, const int* __restrict__ compact,
    const int* __restrict__ bstart, const int* __restrict__ cnt,
    const short* __restrict__ we1p, const short* __restrict__ weap,
    const short* __restrict__ wemp, const float* __restrict__ asrcb,
    const unsigned short* __restrict__ adst_bf, const float* __restrict__ hmb,
    const float* __restrict__ wa2, const float* __restrict__ be1,
    const float* __restrict__ ba2, const float* __restrict__ bea,
    const float* __restrict__ bem, float* __restrict__ aggp,
    float2* __restrict__ msbuf) {
  const int nv = cnt[0];
  const int v = blockIdx.x >> 2;
  if (v >= nv) return;
  const int q = blockIdx.x & 3;
  const int blk = compact[v];
  const int b = blk >> 8;
  const int jb0 = bstart[b];
  const int nb = bstart[b + 1] - jb0;
  const int tid = threadIdx.x;

  if (q * 64 >= nb) {  // unused chunk: deterministic zero-fill for kernD merge
    if (tid < 128) aggp[((size_t)blk * 4 + q) * 128 + tid] = 0.f;
    if (tid == 0) msbuf[blk * 4 + q] = make_float2(-1e30f, 0.f);
    return;
  }

  __shared__ short Tl[64 * 128];                  // 16KB, XOR-swizzled rows
  __shared__ float att2[2][64];
  __shared__ float wtil[64];
  __shared__ __align__(16) float asr_s[128], hm_s[128], wa2_s[128];
  __shared__ float be1_s[128];
  __shared__ __align__(16) float agg2[2][128];

  const int w = tid >> 6, l = tid & 63;
  const int l15 = l & 15, l4 = l >> 4;
  const int jh = w >> 1, hh = w & 1;

  // valid-j row indices for this lane's T rows, then EF loads (early issue)
  int jrow[2];
  float4 f0[2], f1[2];
#pragma unroll
  for (int m = 0; m < 2; ++m) {
    int idx = q * 64 + 32 * jh + 16 * m + l15;
    jrow[m] = compact[jb0 + (idx < nb ? idx : nb - 1)] & 255;
    const float* p = ef + (((size_t)blk * 256 + jrow[m]) * 32 + 8 * l4);
    f0[m] = *(const float4*)p;
    f1[m] = *(const float4*)(p + 4);
  }

  if (tid < 128) {
    asr_s[tid] = asrcb[(size_t)blk * 128 + tid] + bea[tid];
    hm_s[tid] = hmb[(size_t)blk * 128 + tid] + bem[tid];
    wa2_s[tid] = wa2[tid];
    be1_s[tid] = be1[tid];
  }
  __syncthreads();

  const float ba2v = ba2[0];
  const float RS = 0.08838834764831845f;          // 1/sqrt(128)
  const f32x4 vz = {0.f, 0.f, 0.f, 0.f};
  const f32x4 asv = *(const f32x4*)&asr_s[hh * 64 + 4 * l15];
  const f32x4 wav = *(const f32x4*)&wa2_s[hh * 64 + 4 * l15];
  float whalf = wav[0] + wav[1] + wav[2] + wav[3];
  whalf += __shfl_xor(whalf, 1);
  whalf += __shfl_xor(whalf, 2);
  whalf += __shfl_xor(whalf, 4);
  whalf += __shfl_xor(whalf, 8);

  // ---- T = relu(EF @ We1 + be1) -> Tl (swizzled) ----
  {
    f32x4 acc[2][4];
#pragma unroll
    for (int m = 0; m < 2; ++m)
#pragma unroll
      for (int n = 0; n < 4; ++n) acc[m][n] = vz;
#pragma unroll
    for (int m = 0; m < 2; ++m) {
      union { bhalf8 v8; unsigned u[4]; } a;
      a.u[0] = cvt_pk(f0[m].x, f0[m].y);
      a.u[1] = cvt_pk(f0[m].z, f0[m].w);
      a.u[2] = cvt_pk(f1[m].x, f1[m].y);
      a.u[3] = cvt_pk(f1[m].z, f1[m].w);
#pragma unroll
      for (int n = 0; n < 4; ++n) {
        bhalf8 bfr = *(const bhalf8*)(we1p + (size_t)((hh * 4 + n) * 64 + l) * 8);
        acc[m][n] = mfma16(a.v8, bfr, acc[m][n]);
      }
    }
#pragma unroll
    for (int m = 0; m < 2; ++m)
#pragma unroll
      for (int n = 0; n < 4; ++n) {
        int hc = hh * 64 + 16 * n + l15;
        float bias = be1_s[hc];
#pragma unroll
        for (int r = 0; r < 4; ++r) {
          int jl = 32 * jh + 16 * m + 4 * l4 + r;
          float vv = fmaxf(acc[m][n][r] + bias, 0.f);
          int byte = (jl * 256 + 2 * hc) ^ ((jl & 7) << 4);
          *(short*)((char*)Tl + byte) = (short)(cvt_pk(vv, vv) & 0xffff);
        }
      }
  }
  __syncthreads();

  // ---- attention logits: EA = T @ Wea ----
  {
    ushort4 adp[2][4];
#pragma unroll
    for (int m = 0; m < 2; ++m)
#pragma unroll
      for (int r = 0; r < 4; ++r) {
        int idx = q * 64 + 32 * jh + 16 * m + 4 * l4 + r;
        int jg = compact[jb0 + (idx < nb ? idx : nb - 1)] & 255;
        adp[m][r] = *(const ushort4*)(adst_bf + (size_t)(b * 256 + jg) * 128 +
                                      hh * 64 + 4 * l15);
      }
    f32x4 acc[2][4];
#pragma unroll
    for (int m = 0; m < 2; ++m)
#pragma unroll
      for (int n = 0; n < 4; ++n) acc[m][n] = vz;
#pragma unroll
    for (int ks = 0; ks < 4; ++ks) {
      bhalf8 af[2];
#pragma unroll
      for (int m = 0; m < 2; ++m) {
        int jl = 32 * jh + 16 * m + l15;
        int byte = (jl * 256 + ks * 64 + 16 * l4) ^ ((jl & 7) << 4);
        af[m] = *(const bhalf8*)((const char*)Tl + byte);
      }
#pragma unroll
      for (int n = 0; n < 4; ++n) {
        bhalf8 bf2 = *(const bhalf8*)(weap + (size_t)((ks * 8 + hh * 4 + n) * 64 + l) * 8);
#pragma unroll
        for (int m = 0; m < 2; ++m) acc[m][n] = mfma16(af[m], bf2, acc[m][n]);
      }
    }
    // sum_h wa2*tanh(x) = whalf - 2*sum_h wa2 * rcp(exp2(2log2e*x) + 1)
#pragma unroll
    for (int m = 0; m < 2; ++m)
#pragma unroll
      for (int r = 0; r < 4; ++r) {
        float racc = 0.f;
        float adv[4] = {bf2f(adp[m][r].x), bf2f(adp[m][r].y),
                        bf2f(adp[m][r].z), bf2f(adp[m][r].w)};
#pragma unroll
        for (int n = 0; n < 4; ++n) {
          float x = acc[m][n][r] + asv[n] + adv[n];
          float e = rawexp2(x * 2.885390082f);    // e^(2x)
          racc = fmaf(wav[n], rawrcp(e + 1.f), racc);
        }
        racc += __shfl_xor(racc, 1);
        racc += __shfl_xor(racc, 2);
        racc += __shfl_xor(racc, 4);
        racc += __shfl_xor(racc, 8);
        if (l15 == 0)
          att2[hh][32 * jh + 16 * m + 4 * l4 + r] = whalf - 2.f * racc;
      }
  }
  __syncthreads();

  // ---- partial softmax over this chunk's 64 slots (wave 0) ----
  if (w == 0) {
    int idx = q * 64 + l;
    float s = (idx < nb) ? (att2[0][l] + att2[1][l] + ba2v) * RS : -1e30f;
    float mx = s;
#pragma unroll
    for (int o = 1; o < 64; o <<= 1) mx = fmaxf(mx, __shfl_xor(mx, o));
    float e = __expf(s - mx);
    wtil[l] = e;
    float sm = e;
#pragma unroll
    for (int o = 1; o < 64; o <<= 1) sm += __shfl_xor(sm, o);
    if (l == 0) msbuf[blk * 4 + q] = make_float2(mx, sm);
  }
  __syncthreads();

  // ---- message: EM = T @ Wem ; weighted relu-agg (unnormalized) ----
  {
    const f32x4 hv = *(const f32x4*)&hm_s[hh * 64 + 4 * l15];
    f32x4 acc[2][4];
#pragma unroll
    for (int m = 0; m < 2; ++m)
#pragma unroll
      for (int n = 0; n < 4; ++n) acc[m][n] = vz;
#pragma unroll
    for (int ks = 0; ks < 4; ++ks) {
      bhalf8 af[2];
#pragma unroll
      for (int m = 0; m < 2; ++m) {
        int jl = 32 * jh + 16 * m + l15;
        int byte = (jl * 256 + ks * 64 + 16 * l4) ^ ((jl & 7) << 4);
        af[m] = *(const bhalf8*)((const char*)Tl + byte);
      }
#pragma unroll
      for (int n = 0; n < 4; ++n) {
        bhalf8 bf2 = *(const bhalf8*)(wemp + (size_t)((ks * 8 + hh * 4 + n) * 64 + l) * 8);
#pragma unroll
        for (int m = 0; m < 2; ++m) acc[m][n] = mfma16(af[m], bf2, acc[m][n]);
      }
    }
    float part[4] = {0.f, 0.f, 0.f, 0.f};
#pragma unroll
    for (int m = 0; m < 2; ++m)
#pragma unroll
      for (int r = 0; r < 4; ++r) {
        int jl = 32 * jh + 16 * m + 4 * l4 + r;
        float wj = wtil[jl];
#pragma unroll
        for (int n = 0; n < 4; ++n) {
          float vv = fmaxf(acc[m][n][r] + hv[n], 0.f);
          part[n] = fmaf(wj, vv, part[n]);
        }
      }
#pragma unroll
    for (int n = 0; n < 4; ++n) {
      part[n] += __shfl_xor(part[n], 16);
      part[n] += __shfl_xor(part[n], 32);
    }
    if (l4 == 0) {
      f32x4 pv = {part[0], part[1], part[2], part[3]};
      *(f32x4*)&agg2[jh][hh * 64 + 4 * l15] = pv;
    }
  }
  __syncthreads();
  if (tid < 128)
    aggp[((size_t)blk * 4 + q) * 128 + tid] = agg2[0][tid] + agg2[1][tid];
}

// ---------------------------------------------------------------------------
// Kernel D v2: 8 nodes/block, 1024 threads = (col 0..127, node g 0..7).
// One output element per thread per pass; 16 waves/block for latency hiding.
// merge chunks -> agg; agg@Wm2; out-MLP; residual; wave-level LayerNorm; mask.
// ---------------------------------------------------------------------------
__global__ __launch_bounds__(1024) void kernD(
    const float* __restrict__ hsrc, const int* __restrict__ vmask,
    const float* __restrict__ aggp, const float2* __restrict__ msbuf,
    const float* __restrict__ Wm2, const float* __restrict__ bm2,
    const float* __restrict__ Wo1, const float* __restrict__ bo1,
    const float* __restrict__ Wo2, const float* __restrict__ bo2,
    const float* __restrict__ gma, const float* __restrict__ bta,
    float* __restrict__ outp) {
  __shared__ float hL[8][128], xL[8][128], uL[8][128], rL[8][128];
  __shared__ float2 lnr[8][2];
  const int tid = threadIdx.x;
  const int col = tid & 127, g = tid >> 7;    // g = node within block
  const int base = blockIdx.x * 8;
  const int node = base + g;

  // load h; merge partial-softmax chunks -> normalized agg
  hL[g][col] = hsrc[(size_t)node * 128 + col];
  float xv = 0.f;
  if (vmask[node]) {
    float2 ms0 = msbuf[node * 4 + 0], ms1 = msbuf[node * 4 + 1];
    float2 ms2 = msbuf[node * 4 + 2], ms3 = msbuf[node * 4 + 3];
    float m = fmaxf(fmaxf(ms0.x, ms1.x), fmaxf(ms2.x, ms3.x));
    float w0 = __expf(ms0.x - m), w1 = __expf(ms1.x - m);
    float w2 = __expf(ms2.x - m), w3 = __expf(ms3.x - m);
    float den = w0 * ms0.y + w1 * ms1.y + w2 * ms2.y + w3 * ms3.y;
    size_t ab = (size_t)node * 512 + col;
    float num = w0 * aggp[ab] + w1 * aggp[ab + 128] + w2 * aggp[ab + 256] +
                w3 * aggp[ab + 384];
    xv = num / den;
  }
  xL[g][col] = xv;
  __syncthreads();

  // pass 1: uL = xL @ Wm2 + bm2
  float a = 0.f;
#pragma unroll 8
  for (int k = 0; k < 128; k += 4) {
    const float4 x4 = *(const float4*)&xL[g][k];
    a = fmaf(x4.x, Wm2[(k + 0) * 128 + col], a);
    a = fmaf(x4.y, Wm2[(k + 1) * 128 + col], a);
    a = fmaf(x4.z, Wm2[(k + 2) * 128 + col], a);
    a = fmaf(x4.w, Wm2[(k + 3) * 128 + col], a);
  }
  uL[g][col] = a + bm2[col];
  __syncthreads();

  // pass 2: rL = relu(hL@Wo1[:128] + uL@Wo1[128:] + bo1)
  a = 0.f;
#pragma unroll 8
  for (int k = 0; k < 128; k += 4) {
    const float4 h4 = *(const float4*)&hL[g][k];
    a = fmaf(h4.x, Wo1[(k + 0) * 128 + col], a);
    a = fmaf(h4.y, Wo1[(k + 1) * 128 + col], a);
    a = fmaf(h4.z, Wo1[(k + 2) * 128 + col], a);
    a = fmaf(h4.w, Wo1[(k + 3) * 128 + col], a);
  }
#pragma unroll 8
  for (int k = 0; k < 128; k += 4) {
    const float4 u4 = *(const float4*)&uL[g][k];
    a = fmaf(u4.x, Wo1[(128 + k + 0) * 128 + col], a);
    a = fmaf(u4.y, Wo1[(128 + k + 1) * 128 + col], a);
    a = fmaf(u4.z, Wo1[(128 + k + 2) * 128 + col], a);
    a = fmaf(u4.w, Wo1[(128 + k + 3) * 128 + col], a);
  }
  rL[g][col] = fmaxf(a + bo1[col], 0.f);
  __syncthreads();

  // pass 3: xL = hL + rL @ Wo2 + bo2  (residual)
  a = 0.f;
#pragma unroll 8
  for (int k = 0; k < 128; k += 4) {
    const float4 r4 = *(const float4*)&rL[g][k];
    a = fmaf(r4.x, Wo2[(k + 0) * 128 + col], a);
    a = fmaf(r4.y, Wo2[(k + 1) * 128 + col], a);
    a = fmaf(r4.z, Wo2[(k + 2) * 128 + col], a);
    a = fmaf(r4.w, Wo2[(k + 3) * 128 + col], a);
  }
  xL[g][col] = hL[g][col] + a + bo2[col];
  __syncthreads();

  // LayerNorm: wave w (0..15) -> node w>>1, col half w&1. E[x^2]-mu^2 form.
  const int w = tid >> 6, l = tid & 63;
  const int gg = w >> 1, hf = w & 1, cc = 64 * hf + l;
  float x = xL[gg][cc];
  float s = x, ss = x * x;
#pragma unroll
  for (int o = 1; o < 64; o <<= 1) {
    s += __shfl_xor(s, o);
    ss += __shfl_xor(ss, o);
  }
  if (l == 0) lnr[gg][hf] = make_float2(s, ss);
  __syncthreads();
  const float2 A = lnr[gg][0], Bv = lnr[gg][1];
  const float S = A.x + Bv.x, SS = A.y + Bv.y;
  const float mu = S * (1.f / 128.f);
  const float var = SS * (1.f / 128.f) - mu * mu;
  const float inv = rsqrtf(var + 1e-5f);
  const int nd = base + gg;
  const int valid = vmask[nd];
  float o0 = valid ? (x - mu) * inv * gma[cc] + bta[cc] : 0.f;
  outp[(size_t)nd * 128 + cc] = o0;
}

// ---------------------------------------------------------------------------
extern "C" void kernel_launch(void* const* d_in, const int* in_sizes, int n_in,
                              void* d_out, int out_size, void* d_ws, size_t ws_size,
                              hipStream_t stream) {
  const float* h_in = (const float*)d_in[0];
  const float* ef = (const float*)d_in[1];
  const int* vmask = (const int*)d_in[2];
  const float* We1 = (const float*)d_in[3];
  const float* be1 = (const float*)d_in[4];
  const float* We2 = (const float*)d_in[5];
  const float* be2 = (const float*)d_in[6];
  const float* Wa1 = (const float*)d_in[7];
  const float* ba1 = (const float*)d_in[8];
  const float* Wa2 = (const float*)d_in[9];
  const float* ba2 = (const float*)d_in[10];
  const float* Wm1 = (const float*)d_in[11];
  const float* bm1 = (const float*)d_in[12];
  const float* Wm2 = (const float*)d_in[13];
  const float* bm2 = (const float*)d_in[14];
  const float* Wo1 = (const float*)d_in[15];
  const float* bo1 = (const float*)d_in[16];
  const float* Wo2 = (const float*)d_in[17];
  const float* bo2 = (const float*)d_in[18];
  const float* gma = (const float*)d_in[19];
  const float* bta = (const float*)d_in[20];

  char* ws = (char*)d_ws;
  short* we1p = (short*)(ws + 0);                    // 8192 B
  short* weap = (short*)(ws + 8192);                 // 32768 B
  short* wemp = (short*)(ws + 40960);                // 32768 B
  float* bea = (float*)(ws + 73728);                 // 512 B
  float* bem = (float*)(ws + 74240);                 // 512 B
  int* compact = (int*)(ws + 74752);                 // 8192 B
  int* bstart = (int*)(ws + 82944);                  // 64 B (9 ints)
  int* cnt = (int*)(ws + 83072);                     // 64 B
  float* asrcb = (float*)(ws + 83136);               // 1 MiB
  float* hmb = (float*)(ws + 83136 + 1048576);       // 1 MiB
  unsigned short* adst_bf = (unsigned short*)(ws + 83136 + 2097152);  // 512 KiB
  float* aggp = (float*)(ws + 83136 + 2621440);      // 4 MiB
  float2* msbuf = (float2*)(ws + 83136 + 2621440 + 4194304);  // 64 KiB

  fusedPre<<<dim3(402), dim3(256), 0, stream>>>(
      h_in, vmask, We1, We2, be2, Wa1, ba1, Wm1, bm1, we1p, weap, wemp, bea,
      bem, compact, bstart, cnt, asrcb, adst_bf, hmb);
  kernC<<<dim3(8192), dim3(256), 0, stream>>>(ef, compact, bstart, cnt, we1p,
                                              weap, wemp, asrcb, adst_bf, hmb,
                                              Wa2, be1, ba2, bea, bem, aggp,
                                              msbuf);
  kernD<<<dim3(256), dim3(1024), 0, stream>>>(h_in, vmask, aggp, msbuf, Wm2,
                                              bm2, Wo1, bo1, Wo2, bo2, gma,
                                              bta, (float*)d_out);
}